// Round 13
// baseline (3078.415 us; speedup 1.0000x reference)
//
#include <hip/hip_runtime.h>
#include <hip/hip_cooperative_groups.h>
#include <cmath>

namespace cg = cooperative_groups;

typedef unsigned short u16;
typedef __bf16 bf16x8 __attribute__((ext_vector_type(8)));
typedef float f32x4 __attribute__((ext_vector_type(4)));
typedef float f32x16 __attribute__((ext_vector_type(16)));
typedef u16 u16x4 __attribute__((ext_vector_type(4)));
typedef u16 u16x2 __attribute__((ext_vector_type(2)));
typedef u16 u16x8 __attribute__((ext_vector_type(8)));

#define GLOAD16(g, l) __builtin_amdgcn_global_load_lds( \
    (const __attribute__((address_space(1))) unsigned int*)(g), \
    (__attribute__((address_space(3))) unsigned int*)(l), 16, 0, 0)

__device__ __forceinline__ u16 f2b(float f) {
  unsigned u = __builtin_bit_cast(unsigned, f);
  unsigned r = (u + 0x7fffu + ((u >> 16) & 1u)) >> 16;
  return (u16)r;
}

// XCD-aware bijective swizzle (m204)
__device__ __forceinline__ int xcd_swz(int lin, int nwg) {
  int q = nwg >> 3, r = nwg & 7;
  int xcd = lin & 7, idx = lin >> 3;
  return xcd * q + (xcd < r ? xcd : r) + idx;
}

// ---------------- 32x32 transpose tile (fallback path only)
__device__ __forceinline__ void trans_tile(const float* __restrict__ W, u16* __restrict__ Wo,
                                           int K, int N, int Kp, int n0, int k0)
{
  __shared__ float t[32][33];
  int tx = threadIdx.x & 31, ty = threadIdx.x >> 5;
  #pragma unroll
  for (int i = 0; i < 4; ++i) {
    int k = k0 + ty + i * 8;
    t[ty + i * 8][tx] = (k < K) ? W[(long)k * N + n0 + tx] : 0.0f;
  }
  __syncthreads();
  #pragma unroll
  for (int i = 0; i < 2; ++i) {
    int p = threadIdx.x + 256 * i;
    int nl = p >> 4, kk = (p & 15) * 2;
    u16x2 o2; o2[0] = f2b(t[kk][nl]); o2[1] = f2b(t[kk + 1][nl]);
    *(u16x2*)(Wo + (long)(n0 + nl) * Kp + k0 + kk) = o2;
  }
}

// ---------------- single batched transpose, 64x64 tiles, formula-addressed
__global__ __launch_bounds__(256)
void transall_k(const float* wq0, const float* wk0, const float* wv0, const float* wo0,
                const float* fc0, const float* pr0,
                const float* wq1, const float* wk1, const float* wv1, const float* wo1,
                const float* fc1, const float* pr1,
                const float* hu, const float* hd, const float* cw,
                u16* qkvt, u16* wot, u16* fct, u16* prt, u16* hutd, u16* cwt)
{
  int bid = blockIdx.x;
  const float* src; u16* dst; int K, N, Kp, t, tilesX;
  if (bid < 20736) {
    int l = bid / 1728, local = bid - l * 1728;
    int s = l / 6, li = l - s * 6;
    if (local < 432) {
      int p = local / 144; t = local - p * 144;
      const float* base = (p == 0) ? (s ? wq1 : wq0) : (p == 1) ? (s ? wk1 : wk0) : (s ? wv1 : wv0);
      src = base + (size_t)li * 768 * 768;
      dst = qkvt + (size_t)l * 2304 * 768 + (size_t)p * 768 * 768;
      K = 768; N = 768; Kp = 768; tilesX = 12;
    } else if (local < 576) {
      t = local - 432;
      src = (s ? wo1 : wo0) + (size_t)li * 768 * 768;
      dst = wot + (size_t)l * 768 * 768;
      K = 768; N = 768; Kp = 768; tilesX = 12;
    } else if (local < 1152) {
      t = local - 576;
      src = (s ? fc1 : fc0) + (size_t)li * 768 * 3072;
      dst = fct + (size_t)l * 3072 * 768;
      K = 768; N = 3072; Kp = 768; tilesX = 48;
    } else {
      t = local - 1152;
      src = (s ? pr1 : pr0) + (size_t)li * 3072 * 768;
      dst = prt + (size_t)l * 768 * 3072;
      K = 3072; N = 768; Kp = 3072; tilesX = 12;
    }
  } else {
    int e = bid - 20736;
    if (e < 96)       { t = e;       src = hu; dst = hutd;             K = 768; N = 512; Kp = 768; tilesX = 8; }
    else if (e < 192) { t = e - 96;  src = hd; dst = hutd + 512 * 768; K = 768; N = 512; Kp = 768; tilesX = 8; }
    else              { t = e - 192; src = cw; dst = cwt;              K = 438; N = 768; Kp = 448; tilesX = 12; }
  }
  int n0 = (t % tilesX) * 64, k0 = (t / tilesX) * 64;

  __shared__ float tl[64][65];
  const int tid = threadIdx.x;
  const int c4 = (tid & 15) * 4, rbase = tid >> 4;
  #pragma unroll
  for (int p = 0; p < 4; ++p) {
    int r = rbase + p * 16;
    int k = k0 + r;
    float4 v = make_float4(0.0f, 0.0f, 0.0f, 0.0f);
    if (k < K) v = *(const float4*)(src + (long)k * N + n0 + c4);
    tl[r][c4] = v.x; tl[r][c4 + 1] = v.y; tl[r][c4 + 2] = v.z; tl[r][c4 + 3] = v.w;
  }
  __syncthreads();
  const int kg = (tid & 7) * 8, nbase = tid >> 3;
  #pragma unroll
  for (int p = 0; p < 2; ++p) {
    int n = nbase + p * 32;
    u16x8 pk;
    #pragma unroll
    for (int j = 0; j < 8; ++j) pk[j] = f2b(tl[kg + j][n]);
    *(u16x8*)(dst + (long)(n0 + n) * Kp + k0 + kg) = pk;
  }
}

// single-matrix transpose (fallback !up path)
__global__ __launch_bounds__(256)
void transw_k(const float* __restrict__ W, u16* __restrict__ Wt,
              int K, int N, int Kp, long sIn, long sOut)
{
  int l = blockIdx.z;
  trans_tile(W + (long)l * sIn, Wt + (long)l * sOut, K, N, Kp, blockIdx.x * 32, blockIdx.y * 32);
}

// ---------------- merged prologue: biascat | condcvt x4 | embed f4
__global__ __launch_bounds__(256)
void prep_k(const float* bq0, const float* bk0, const float* bv0,
            const float* bq1, const float* bk1, const float* bv1, float* qkvb,
            const float* cond, u16* cbf,
            const int* iu, const int* idn, const float* teu, const float* ted,
            const float* pe, float* x)
{
  int idx = blockIdx.x * 256 + threadIdx.x;
  if (idx < 27648) {
    int c = idx % 2304, l = idx / 2304;
    int st = l / 6, li = l % 6;
    const float* src = (c < 768) ? (st ? bq1 : bq0) : (c < 1536) ? (st ? bk1 : bk0) : (st ? bv1 : bv0);
    qkvb[idx] = src[li * 768 + (c % 768)];
  } else if (idx < 27648 + 57344) {
    int i2 = idx - 27648;
    int r = i2 / 112, kk = (i2 - r * 112) * 4;
    u16x4 pk;
    #pragma unroll
    for (int i = 0; i < 4; ++i) { int k = kk + i; pk[i] = f2b(k < 438 ? cond[r * 438 + k] : 0.0f); }
    *(u16x4*)(cbf + r * 448 + kk) = pk;
  } else if (idx < 27648 + 57344 + 196608) {
    int i3 = idx - 27648 - 57344;
    int c4 = i3 % 192; int rest = i3 / 192;
    int tt = rest % 512; int b = rest / 512;
    int i = tt & 255; int s = tt >> 8;
    int tok = s ? idn[b * 256 + i] : iu[b * 256 + i];
    const float4* src = (const float4*)(s ? (ted + (long)tok * 768) : (teu + (long)tok * 768));
    int prow = 256 + s * 256 + i;
    float4 pv = ((const float4*)(pe + (long)prow * 768))[c4];
    float4 sv = src[c4];
    float4 ov; ov.x = sv.x + pv.x; ov.y = sv.y + pv.y; ov.z = sv.z + pv.z; ov.w = sv.w + pv.w;
    ((float4*)(x + ((long)b * 768 + prow) * 768))[c4] = ov;
  }
}

// ---------------- LN row body: x_new = xin + sum P + bias; h = LN(x_new)*g+b
template<int S, bool WX>
__device__ __forceinline__ void ln_row(int row, const float* __restrict__ xin,
                                       const float* __restrict__ P, const float* __restrict__ bias,
                                       const float* __restrict__ gg, const float* __restrict__ bb,
                                       float* __restrict__ xout, u16* __restrict__ h)
{
  int lane = threadIdx.x & 63;
  long base = (long)row * 768;
  const float4* xr4 = (const float4*)(xin + base);
  float4 v[3]; float s = 0.0f;
  #pragma unroll
  for (int j = 0; j < 3; ++j) {
    int f = lane + 64 * j;
    float4 val = xr4[f];
    if (S > 0) {
      float4 bv = ((const float4*)bias)[f];
      val.x += bv.x; val.y += bv.y; val.z += bv.z; val.w += bv.w;
      #pragma unroll
      for (int si = 0; si < S; ++si) {
        float4 pv = ((const float4*)(P + (long)si * 1179648 + base))[f];
        val.x += pv.x; val.y += pv.y; val.z += pv.z; val.w += pv.w;
      }
    }
    if (WX) ((float4*)(xout + base))[f] = val;
    v[j] = val; s += val.x + val.y + val.z + val.w;
  }
  #pragma unroll
  for (int d = 1; d < 64; d <<= 1) s += __shfl_xor(s, d);
  float mean = s * (1.0f / 768.0f);
  float s2 = 0.0f;
  #pragma unroll
  for (int j = 0; j < 3; ++j) {
    float dx = v[j].x - mean, dy = v[j].y - mean, dz = v[j].z - mean, dw = v[j].w - mean;
    s2 += dx * dx + dy * dy + dz * dz + dw * dw;
  }
  #pragma unroll
  for (int d = 1; d < 64; d <<= 1) s2 += __shfl_xor(s2, d);
  float rstd = rsqrtf(s2 * (1.0f / 768.0f) + 1e-5f);
  u16* orow = h + base;
  #pragma unroll
  for (int j = 0; j < 3; ++j) {
    int f = lane + 64 * j;
    float4 gv = ((const float4*)gg)[f];
    float4 bv2 = ((const float4*)bb)[f];
    u16x4 pk;
    pk[0] = f2b((v[j].x - mean) * rstd * gv.x + bv2.x);
    pk[1] = f2b((v[j].y - mean) * rstd * gv.y + bv2.y);
    pk[2] = f2b((v[j].z - mean) * rstd * gv.z + bv2.z);
    pk[3] = f2b((v[j].w - mean) * rstd * gv.w + bv2.w);
    *(u16x4*)(orow + 4 * f) = pk;
  }
}

// ---------------- heads reduce: HP [4][512][1024] -> out [2][512][512]
__global__ __launch_bounds__(256)
void headred_k(const float* __restrict__ HP, float* __restrict__ out)
{
  int i4 = blockIdx.x * 256 + threadIdx.x;
  int st = i4 >> 16, loc = i4 & 65535;
  int r = loc >> 7, c4 = loc & 127;
  const float4* basep = (const float4*)HP + (long)r * 256 + st * 128 + c4;
  float4 a = basep[0], b = basep[131072], c = basep[2 * 131072], d = basep[3 * 131072];
  float4 rr; rr.x = a.x + b.x + c.x + d.x; rr.y = a.y + b.y + c.y + d.y;
  rr.z = a.z + b.z + c.z + d.z; rr.w = a.w + b.w + c.w + d.w;
  ((float4*)out)[i4] = rr;
}

// ---------------- GEMM body: C[M,N] = A[M,K](bf16) @ Bt[N,K](bf16)^T
#define EPI_PLAIN 0
#define EPI_PE    1
#define EPI_QKV   2
#define EPI_GELU  4
#define EPI_PART  5
#define EPI_HEAD  6

template<int BM, int BN, int WM, int WN, int EPI, bool BIAS>
__device__ __forceinline__
void gemm_body(u16* Sl, int lin, int gx, int gy, int nwg,
               const u16* __restrict__ A, const u16* __restrict__ Bt, const float* __restrict__ bias,
               float* outf, u16* outb, u16* qb, u16* kb, u16* vT, const float* aux,
               int M, int N, int Ks, int lda, int ldb, int ldc,
               int astr, int aoff, int cstr, int coff, int pstr)
{
  constexpr int NWC = BN / WN;
  constexpr int NT  = (BM / WM) * NWC * 64;
  constexpr int LCH = (BM + BN) * 8;
  constexpr int LPT = LCH / NT;
  constexpr int MR = WM / 32, NR = WN / 32;
  constexpr int BUFE = (BM + BN) * 64;   // u16 elems per buffer

  const int tid = threadIdx.x;
  const int wg = xcd_swz(lin, nwg);
  const int bx = wg % gx, t1g = wg / gx;
  const int by = t1g % gy, bz = t1g / gy;
  const int m0 = bx * BM, n0 = by * BN;
  const int koff = bz * Ks;
  const int lane = tid & 63, w = tid >> 6;
  const int l31 = lane & 31, hl = lane >> 5;
  const int wr = w / NWC, wc = w % NWC;
  int aoffE = aoff;
  if constexpr (EPI == EPI_HEAD) aoffE += (by >= (gy >> 1)) ? 256 : 0;

  const u16* gp[LPT]; int lbase[LPT];
  #pragma unroll
  for (int j = 0; j < LPT; ++j) {
    int c = tid + NT * j;
    int slot = c & 7;
    if (c < BM * 8) {
      int row = c >> 3;
      int se = (slot ^ (row & 7)) * 8;
      int am = m0 + row;
      gp[j] = A + (long)((am >> 8) * astr + aoffE + (am & 255)) * lda + koff + se;
    } else {
      int rb = c - BM * 8;
      int row = rb >> 3;
      int se = (slot ^ (row & 7)) * 8;
      gp[j] = Bt + (long)(n0 + row) * ldb + koff + se;
    }
    lbase[j] = w * 512 + NT * 8 * j;
  }

  int offA[4][MR], offB[4][NR];
  #pragma unroll
  for (int kst = 0; kst < 4; ++kst) {
    int s = 2 * kst + hl;
    #pragma unroll
    for (int mi = 0; mi < MR; ++mi) {
      int r = wr * WM + mi * 32 + l31;
      offA[kst][mi] = r * 128 + ((s ^ (r & 7)) << 4);
    }
    #pragma unroll
    for (int ni = 0; ni < NR; ++ni) {
      int r = wc * WN + ni * 32 + l31;
      offB[kst][ni] = BM * 128 + r * 128 + ((s ^ (r & 7)) << 4);
    }
  }

  f32x16 acc[MR][NR];
  #pragma unroll
  for (int mi = 0; mi < MR; ++mi)
  #pragma unroll
  for (int ni = 0; ni < NR; ++ni) acc[mi][ni] = f32x16{};

  auto STAGE = [&](int kt, int buf) {
    #pragma unroll
    for (int j = 0; j < LPT; ++j) GLOAD16(gp[j] + kt, Sl + buf * BUFE + lbase[j]);
  };
  auto COMPUTE = [&](int buf) {
    const char* Sb = (const char*)Sl + buf * BUFE * 2;
    #pragma unroll
    for (int kst = 0; kst < 4; ++kst) {
      bf16x8 a[MR], b[NR];
      #pragma unroll
      for (int mi = 0; mi < MR; ++mi) a[mi] = *(const bf16x8*)(Sb + offA[kst][mi]);
      #pragma unroll
      for (int ni = 0; ni < NR; ++ni) b[ni] = *(const bf16x8*)(Sb + offB[kst][ni]);
      #pragma unroll
      for (int mi = 0; mi < MR; ++mi)
      #pragma unroll
      for (int ni = 0; ni < NR; ++ni)
        acc[mi][ni] = __builtin_amdgcn_mfma_f32_32x32x16_bf16(a[mi], b[ni], acc[mi][ni], 0, 0, 0);
    }
  };

  const int nIter = Ks >> 6;
  STAGE(0, 0);
  if (nIter > 1) STAGE(64, 1);
  for (int t = 0; t < nIter; ++t) {
    if (t + 1 < nIter) {
      if constexpr (LPT == 8)      asm volatile("s_waitcnt vmcnt(8)" ::: "memory");
      else if constexpr (LPT == 6) asm volatile("s_waitcnt vmcnt(6)" ::: "memory");
      else                         asm volatile("s_waitcnt vmcnt(4)" ::: "memory");
    } else {
      asm volatile("s_waitcnt vmcnt(0)" ::: "memory");
    }
    __builtin_amdgcn_s_barrier();
    COMPUTE(t & 1);
    if (t + 2 < nIter) {
      __builtin_amdgcn_s_barrier();
      STAGE((t + 2) << 6, t & 1);
    }
  }

  // C/D layout (32x32): col = lane&31, row = (reg&3) + 8*(reg>>2) + 4*(lane>>5)
  #pragma unroll
  for (int mi = 0; mi < MR; ++mi)
  #pragma unroll
  for (int ni = 0; ni < NR; ++ni) {
    f32x16 a = acc[mi][ni];
    int col = n0 + wc * WN + ni * 32 + l31;
    float bv = BIAS ? bias[col] : 0.0f;
    int mlb = m0 + wr * WM + mi * 32 + 4 * hl;
    if constexpr (EPI == EPI_QKV) {
      if (col >= 1536) {
        int c2 = col - 1536, hh = c2 >> 6, dd = c2 & 63;
        #pragma unroll
        for (int q = 0; q < 4; ++q) {
          int t0r = mlb + 8 * q;
          int bb2 = t0r >= 768 ? 1 : 0;
          int t0 = t0r - bb2 * 768;
          u16x4 pk;
          #pragma unroll
          for (int r = 0; r < 4; ++r) pk[r] = f2b(a[4 * q + r] + bv);
          *(u16x4*)(vT + (long)((bb2 * 12 + hh) * 64 + dd) * 768 + t0) = pk;
        }
      } else {
        u16* dst = (col < 768) ? (qb + col) : (kb + (col - 768));
        #pragma unroll
        for (int q = 0; q < 4; ++q)
        #pragma unroll
        for (int r = 0; r < 4; ++r) {
          int row = mlb + 8 * q + r;
          dst[(long)row * 768] = f2b(a[4 * q + r] + bv);
        }
      }
    } else {
      #pragma unroll
      for (int q = 0; q < 4; ++q)
      #pragma unroll
      for (int r = 0; r < 4; ++r) {
        int rg = mlb + 8 * q + r;
        long crow = (long)(rg >> 8) * cstr + coff + (rg & 255);
        float v = a[4 * q + r] + bv;
        if (EPI == EPI_PLAIN)      outf[crow * ldc + col] = v;
        else if (EPI == EPI_PE)    outf[crow * ldc + col] = v + aux[(long)(rg & 255) * 768 + col];
        else if (EPI == EPI_PART || EPI == EPI_HEAD)
                                   outf[(long)bz * pstr + (long)rg * ldc + col] = v;
        else if (EPI == EPI_GELU)  outb[crow * ldc + col] = f2b(0.5f * v * (1.0f + erff(v * 0.70710678f)));
      }
    }
  }
}

// ---------------- standalone GEMM kernel (3D grid)
template<int BM, int BN, int WM, int WN, int EPI, bool BIAS>
__global__ __launch_bounds__(256)
void gemm_k(const u16* __restrict__ A, const u16* __restrict__ Bt, const float* __restrict__ bias,
            float* outf, u16* outb, u16* qb, u16* kb, u16* vT, const float* aux,
            int M, int N, int Ks, int lda, int ldb, int ldc,
            int astr, int aoff, int cstr, int coff, int pstr)
{
  __shared__ alignas(16) u16 Sl[2][(BM + BN) * 64];
  const int gx = gridDim.x, gy = gridDim.y;
  const int nwg = gx * gy * gridDim.z;
  const int lin = (blockIdx.z * gy + blockIdx.y) * gx + blockIdx.x;
  gemm_body<BM, BN, WM, WN, EPI, BIAS>(&Sl[0][0], lin, gx, gy, nwg,
      A, Bt, bias, outf, outb, qb, kb, vT, aux,
      M, N, Ks, lda, ldb, ldc, astr, aoff, cstr, coff, pstr);
}

// ---------------- cooperative fused LN -> QKV (grid 432)
template<int S, bool WX>
__global__ __launch_bounds__(256, 3)
void coop_qkv_k(const float* xin, const float* P, const float* pbias,
                const float* gg, const float* bb, float* xout, u16* h,
                const u16* Bt, const float* qbias, u16* qb, u16* kb, u16* vT)
{
  __shared__ alignas(16) u16 Sl[2][(128 + 64) * 64];
  int wid = blockIdx.x * 4 + (threadIdx.x >> 6);
  if (wid < 1536) ln_row<S, WX>(wid, xin, P, pbias, gg, bb, xout, h);
  cg::this_grid().sync();
  gemm_body<128, 64, 32, 64, EPI_QKV, true>(&Sl[0][0], blockIdx.x, 12, 36, 432,
      h, Bt, qbias, nullptr, nullptr, qb, kb, vT, nullptr,
      1536, 2304, 768, 768, 768, 768, 256, 0, 256, 0, 0);
}

// ---------------- cooperative fused LN2 -> FC (grid 576)
__global__ __launch_bounds__(256, 3)
void coop_fc_k(const float* xin, const float* P, const float* pbias,
               const float* gg, const float* bb, float* xout, u16* h,
               const u16* Bt, const float* fcbias, u16* fca)
{
  __shared__ alignas(16) u16 Sl[2][(128 + 64) * 64];
  int wid = blockIdx.x * 4 + (threadIdx.x >> 6);
  if (wid < 1536) ln_row<2, true>(wid, xin, P, pbias, gg, bb, xout, h);
  cg::this_grid().sync();
  gemm_body<128, 64, 32, 64, EPI_GELU, true>(&Sl[0][0], blockIdx.x, 12, 48, 576,
      h, Bt, fcbias, nullptr, fca, nullptr, nullptr, nullptr, nullptr,
      1536, 3072, 768, 768, 768, 3072, 256, 0, 256, 0, 0);
}

// ---------------- cooperative fused ln_f -> heads (grid 512)
__global__ __launch_bounds__(256, 3)
void coop_head_k(const float* xin, const float* P, const float* pbias,
                 const float* gg, const float* bb, u16* xf,
                 const u16* Bt, float* HP)
{
  __shared__ alignas(16) u16 Sl[2][(64 + 64) * 64];
  int wid = blockIdx.x * 4 + (threadIdx.x >> 6);
  if (wid < 1536) ln_row<2, false>(wid, xin, P, pbias, gg, bb, nullptr, xf);
  cg::this_grid().sync();
  gemm_body<64, 64, 32, 32, EPI_HEAD, false>(&Sl[0][0], blockIdx.x, 8, 16, 512,
      xf, Bt, nullptr, HP, nullptr, nullptr, nullptr, nullptr, nullptr,
      512, 1024, 192, 768, 768, 1024, 768, 256, 256, 0, 524288);
}

// ---------------- flash attention: 32 q-rows / 2 waves per WG, masked-tile skipping
#define MFMA_BF16 __builtin_amdgcn_mfma_f32_16x16x32_bf16
__global__ __launch_bounds__(128)
void attn_k(const u16* __restrict__ qb, const u16* __restrict__ kb,
            const u16* __restrict__ vT, u16* __restrict__ y)
{
  __shared__ alignas(16) u16 Kl[3 * 4096];
  __shared__ alignas(16) u16 Vl[3 * 4096];
  __shared__ alignas(16) u16 Pl[2][16 * 72];
  const int gx = gridDim.x, gy = gridDim.y;
  const int nwg = gx * gy;
  const int lin = blockIdx.y * gx + blockIdx.x;
  const int wg = xcd_swz(lin, nwg);
  const int qt = wg % gx, bh = wg / gx;
  const int b = bh / 12, h = bh - b * 12;
  const int tid = threadIdx.x, w = tid >> 6, lane = tid & 63, l15 = lane & 15, g = lane >> 4;
  const int qrow = qt * 32 + w * 16 + l15;
  const int qm = qrow & 255;
  const int q0 = (qt * 32) & 255;
  const unsigned nw4 = (q0 >> 6) + 1;
  const int niter = 3 * nw4;
  const u16* qp = qb + (long)(b * 768 + qrow) * 768 + h * 64;
  bf16x8 qf0 = *(const bf16x8*)(qp + 8 * g);
  bf16x8 qf1 = *(const bf16x8*)(qp + 32 + 8 * g);
  f32x4 O0{}, O1{}, O2{}, O3{};
  float m_run = -1e30f, l_run = 0.0f;

  const u16* kp[4]; const u16* vp[4]; int ldsb[4];
  #pragma unroll
  for (int j = 0; j < 4; ++j) {
    int i = tid + 128 * j;
    int r = i >> 3, sl = ((i & 7) ^ (r & 7)) * 8;
    kp[j] = kb + (long)(b * 768 + r) * 768 + h * 64 + sl;
    vp[j] = vT + (long)(bh * 64 + r) * 768 + sl;
    ldsb[j] = (w + 2 * j) * 512;
  }

  auto STAGE = [&](int kt, int q) {
    u16* kd = Kl + q * 4096; u16* vd = Vl + q * 4096;
    #pragma unroll
    for (int j = 0; j < 4; ++j) GLOAD16(kp[j] + (long)kt * 64 * 768, kd + ldsb[j]);
    #pragma unroll
    for (int j = 0; j < 4; ++j) GLOAD16(vp[j] + kt * 64, vd + ldsb[j]);
  };
  auto MAP = [&](int it) {
    unsigned sb = (unsigned)it / nw4;
    return (int)(sb * 4 + ((unsigned)it - sb * nw4));
  };

  STAGE(MAP(0), 0);
  STAGE(MAP(1), 1);
  int cur = 0;
  for (int it = 0; it < niter; ++it) {
    if (it < niter - 1) asm volatile("s_waitcnt vmcnt(8)" ::: "memory");
    else                asm volatile("s_waitcnt vmcnt(0)" ::: "memory");
    __builtin_amdgcn_s_barrier();
    if (it + 2 < niter) STAGE(MAP(it + 2), cur == 0 ? 2 : cur - 1);
    const int kt = MAP(it);
    const char* Kb = (const char*)Kl + cur * 8192;
    const char* Vb = (const char*)Vl + cur * 8192;

    f32x4 s0{}, s1{}, s2{}, s3{};
    #pragma unroll
    for (int ks = 0; ks < 2; ++ks) {
      bf16x8 qf = ks ? qf1 : qf0;
      int sb = ((4 * ks + g) ^ (l15 & 7)) << 4;
      bf16x8 k0 = *(const bf16x8*)(Kb + (0  + l15) * 128 + sb);
      bf16x8 k1 = *(const bf16x8*)(Kb + (16 + l15) * 128 + sb);
      bf16x8 k2 = *(const bf16x8*)(Kb + (32 + l15) * 128 + sb);
      bf16x8 k3 = *(const bf16x8*)(Kb + (48 + l15) * 128 + sb);
      s0 = MFMA_BF16(k0, qf, s0, 0, 0, 0);
      s1 = MFMA_BF16(k1, qf, s1, 0, 0, 0);
      s2 = MFMA_BF16(k2, qf, s2, 0, 0, 0);
      s3 = MFMA_BF16(k3, qf, s3, 0, 0, 0);
    }
    float sv[16]; float tm = -1e30f;
    #pragma unroll
    for (int mt = 0; mt < 4; ++mt) {
      f32x4 sm4 = (mt == 0) ? s0 : (mt == 1) ? s1 : (mt == 2) ? s2 : s3;
      #pragma unroll
      for (int r = 0; r < 4; ++r) {
        int kg = kt * 64 + mt * 16 + 4 * g + r;
        float val = ((kg & 255) <= qm) ? sm4[r] * 0.125f : -1e30f;
        sv[mt * 4 + r] = val; tm = fmaxf(tm, val);
      }
    }
    tm = fmaxf(tm, __shfl_xor(tm, 16));
    tm = fmaxf(tm, __shfl_xor(tm, 32));
    float mn = fmaxf(m_run, tm);
    float alpha = __expf(m_run - mn);
    float ps = 0.0f; u16 pb16[16];
    #pragma unroll
    for (int j = 0; j < 16; ++j) {
      float p = (sv[j] <= -1e29f) ? 0.0f : __expf(sv[j] - mn);
      ps += p; pb16[j] = f2b(p);
    }
    ps += __shfl_xor(ps, 16); ps += __shfl_xor(ps, 32);
    l_run = l_run * alpha + ps; m_run = mn;
    float a0 = __shfl(alpha, 4 * g + 0);
    float a1 = __shfl(alpha, 4 * g + 1);
    float a2 = __shfl(alpha, 4 * g + 2);
    float a3 = __shfl(alpha, 4 * g + 3);
    #pragma unroll
    for (int mt = 0; mt < 4; ++mt) {
      u16x4 pk; pk[0] = pb16[4*mt]; pk[1] = pb16[4*mt+1]; pk[2] = pb16[4*mt+2]; pk[3] = pb16[4*mt+3];
      *(u16x4*)((char*)&Pl[w][0] + l15 * 144 + mt * 32 + 8 * g) = pk;
    }
    O0[0] *= a0; O0[1] *= a1; O0[2] *= a2; O0[3] *= a3;
    O1[0] *= a0; O1[1] *= a1; O1[2] *= a2; O1[3] *= a3;
    O2[0] *= a0; O2[1] *= a1; O2[2] *= a2; O2[3] *= a3;
    O3[0] *= a0; O3[1] *= a1; O3[2] *= a2; O3[3] *= a3;
    asm volatile("s_waitcnt lgkmcnt(0)" ::: "memory");
    __builtin_amdgcn_sched_barrier(0);
    #pragma unroll
    for (int ks = 0; ks < 2; ++ks) {
      bf16x8 pf = *(const bf16x8*)((const char*)&Pl[w][0] + l15 * 144 + 64 * ks + 16 * g);
      int sb = ((4 * ks + g) ^ (l15 & 7)) << 4;
      bf16x8 v0 = *(const bf16x8*)(Vb + (0  + l15) * 128 + sb);
      bf16x8 v1 = *(const bf16x8*)(Vb + (16 + l15) * 128 + sb);
      bf16x8 v2 = *(const bf16x8*)(Vb + (32 + l15) * 128 + sb);
      bf16x8 v3 = *(const bf16x8*)(Vb + (48 + l15) * 128 + sb);
      O0 = MFMA_BF16(pf, v0, O0, 0, 0, 0);
      O1 = MFMA_BF16(pf, v1, O1, 0, 0, 0);
      O2 = MFMA_BF16(pf, v2, O2, 0, 0, 0);
      O3 = MFMA_BF16(pf, v3, O3, 0, 0, 0);
    }
    cur = (cur == 2) ? 0 : cur + 1;
  }
  float n0i = 1.0f / __shfl(l_run, 4 * g + 0);
  float n1i = 1.0f / __shfl(l_run, 4 * g + 1);
  float n2i = 1.0f / __shfl(l_run, 4 * g + 2);
  float n3i = 1.0f / __shfl(l_run, 4 * g + 3);
  long yr = (long)(b * 768 + qt * 32 + w * 16 + 4 * g);
  #pragma unroll
  for (int ni = 0; ni < 4; ++ni) {
    f32x4 Ov = (ni == 0) ? O0 : (ni == 1) ? O1 : (ni == 2) ? O2 : O3;
    int c = h * 64 + ni * 16 + l15;
    y[(yr + 0) * 768 + c] = f2b(Ov[0] * n0i);
    y[(yr + 1) * 768 + c] = f2b(Ov[1] * n1i);
    y[(yr + 2) * 768 + c] = f2b(Ov[2] * n2i);
    y[(yr + 3) * 768 + c] = f2b(Ov[3] * n3i);
  }
}

// ================= host =================
extern "C" void kernel_launch(void* const* d_in, const int* in_sizes, int n_in,
                              void* d_out, int out_size, void* d_ws, size_t ws_size,
                              hipStream_t stream)
{
  (void)in_sizes; (void)n_in; (void)out_size;
  auto F = [&](int i){ return (const float*)d_in[i]; };
  const int* idx_up = (const int*)d_in[0];
  const int* idx_dn = (const int*)d_in[1];
  const float* cond = F(2);
  const float* teu = F(3);
  const float* ted = F(4);
  const float* pe  = F(5);
  const float* cw  = F(6);
  const float* cb  = F(7);
  float* outp = (float*)d_out;
  char* ws = (char*)d_ws;

  size_t o = 0;
  auto take = [&](size_t bytes){ void* p = ws + o; o += bytes; return p; };
  float* x    = (float*)take(4718592);   // [1536][768] f32 residual stream
  u16*   h    = (u16*)take(2359296);     // LN out bf16
  u16*   qbuf = (u16*)take(2359296);
  u16*   kbuf = (u16*)take(2359296);
  u16*   vT   = (u16*)take(2359296);     // [24][64][768]
  u16*   y    = (u16*)take(2359296);
  u16*   fca  = (u16*)take(9437184);     // [1536][3072]
  u16*   xf   = (u16*)take(2359296);
  u16*   cbf  = (u16*)take(458752);      // cond bf16 [512][448]
  float* qkvb = (float*)take(110592);    // [12][2304]
  u16*   hutd = (u16*)take(1572864);     // [1024][768]
  u16*   cwt  = (u16*)take(688128);      // [768][448]
  float* P1   = (float*)take(9437184);   // proj partials  [2][1536][768]
  float* P2   = (float*)take(9437184);   // proj2 partials [2][1536][768]
  float* HP   = (float*)take(8388608);   // head partials  [4][512][1024]
  const size_t WL = 14155776;            // per-layer transposed weights (bytes)
  bool up = (ws_size >= o + 12 * WL);
  size_t nsl = up ? 12 : 1;
  u16* qkvt = (u16*)(ws + o);
  u16* wot  = qkvt + nsl * 2304 * 768;
  u16* fct  = wot  + nsl * 768 * 768;
  u16* prt  = fct  + nsl * 3072 * 768;

  auto trans = [&](const float* src, u16* dst, int K, int N, int Kp, long sIn, long sOut, int nz){
    transw_k<<<dim3(N / 32, Kp / 32, nz), dim3(256), 0, stream>>>(src, dst, K, N, Kp, sIn, sOut);
  };

  if (up) {
    transall_k<<<dim3(21012), dim3(256), 0, stream>>>(
        F(10), F(12), F(14), F(16), F(20), F(22),
        F(26), F(28), F(30), F(32), F(36), F(38),
        F(42), F(43), cw,
        qkvt, wot, fct, prt, hutd, cwt);
  } else {
    trans(F(42), hutd, 768, 512, 768, 0, 0, 1);
    trans(F(43), hutd + 512 * 768, 768, 512, 768, 0, 0, 1);
    trans(cw,    cwt, 438, 768, 448, 0, 0, 1);
  }
  prep_k<<<dim3(1100), dim3(256), 0, stream>>>(
      F(11), F(13), F(15), F(27), F(29), F(31), qkvb,
      cond, cbf, idx_up, idx_dn, teu, ted, pe, x);
  gemm_k<64, 64, 32, 32, EPI_PE, true><<<dim3(8, 12, 1), dim3(256), 0, stream>>>(cbf, cwt, cb,
      x, nullptr, nullptr, nullptr, nullptr, pe,
      512, 768, 448, 448, 448, 768, 256, 0, 768, 0, 0);

  for (int l = 0; l < 12; ++l) {
    int s = l / 6, li = l % 6;
    u16* qkvt_l = qkvt + (up ? (size_t)l : 0) * 2304 * 768;
    u16* wot_l  = wot  + (up ? (size_t)l : 0) * 768 * 768;
    u16* fct_l  = fct  + (up ? (size_t)l : 0) * 3072 * 768;
    u16* prt_l  = prt  + (up ? (size_t)l : 0) * 768 * 3072;
    if (!up) {
      for (int p = 0; p < 3; ++p)
        trans(F(8 + 16*s + 2 + 2*p) + (size_t)li*768*768, qkvt_l + (size_t)p*768*768, 768, 768, 768, 0, 0, 1);
      trans(F(8 + 16*s + 8)  + (size_t)li*768*768,  wot_l, 768, 768, 768, 0, 0, 1);
      trans(F(8 + 16*s + 12) + (size_t)li*768*3072, fct_l, 768, 3072, 768, 0, 0, 1);
      trans(F(8 + 16*s + 14) + (size_t)li*3072*768, prt_l, 3072, 768, 3072, 0, 0, 1);
    }
    // coop1: LN1 (+ prev-layer proj2 reduce) -> QKV
    const float* g1 = F(8+16*s+0) + (size_t)li*768;
    const float* b1 = F(8+16*s+1) + (size_t)li*768;
    const float* qbias = qkvb + (size_t)l*2304;
    if (l == 0) {
      const float* pb = nullptr;
      void* a1[] = {(void*)&x, (void*)&P2, (void*)&pb, (void*)&g1, (void*)&b1,
                    (void*)&x, (void*)&h, (void*)&qkvt_l, (void*)&qbias,
                    (void*)&qbuf, (void*)&kbuf, (void*)&vT};
      hipLaunchCooperativeKernel((const void*)coop_qkv_k<0, false>, dim3(432), dim3(256), a1, 0, stream);
    } else {
      int ps = (l - 1) / 6, pli = (l - 1) % 6;
      const float* pb = F(8+16*ps+15) + (size_t)pli*768;
      void* a1[] = {(void*)&x, (void*)&P2, (void*)&pb, (void*)&g1, (void*)&b1,
                    (void*)&x, (void*)&h, (void*)&qkvt_l, (void*)&qbias,
                    (void*)&qbuf, (void*)&kbuf, (void*)&vT};
      hipLaunchCooperativeKernel((const void*)coop_qkv_k<2, true>, dim3(432), dim3(256), a1, 0, stream);
    }
    attn_k<<<dim3(24, 24), dim3(128), 0, stream>>>(qbuf, kbuf, vT, y);
    // attn out proj: split-K x2 -> P1
    gemm_k<128, 64, 32, 64, EPI_PART, false><<<dim3(12, 12, 2), dim3(256), 0, stream>>>(y, wot_l, nullptr,
        P1, nullptr, nullptr, nullptr, nullptr, nullptr,
        1536, 768, 384, 768, 768, 768, 256, 0, 256, 0, 1179648);
    // coop2: LN2 (P1 reduce + bo) -> FC(+GELU)
    {
      const float* bo = F(8+16*s+9) + (size_t)li*768;
      const float* g2 = F(8+16*s+10) + (size_t)li*768;
      const float* b2 = F(8+16*s+11) + (size_t)li*768;
      const float* fcb = F(8+16*s+13) + (size_t)li*3072;
      void* a2[] = {(void*)&x, (void*)&P1, (void*)&bo, (void*)&g2, (void*)&b2,
                    (void*)&x, (void*)&h, (void*)&fct_l, (void*)&fcb, (void*)&fca};
      hipLaunchCooperativeKernel((const void*)coop_fc_k, dim3(576), dim3(256), a2, 0, stream);
    }
    // MLP out proj: split-K x2 -> P2 (reduced by next coop1 / coop_head)
    gemm_k<128, 64, 32, 64, EPI_PART, false><<<dim3(12, 12, 2), dim3(256), 0, stream>>>(fca, prt_l, nullptr,
        P2, nullptr, nullptr, nullptr, nullptr, nullptr,
        1536, 768, 1536, 3072, 3072, 768, 256, 0, 256, 0, 1179648);
  }
  // coop3: ln_f (last proj2 reduce) -> merged heads GEMM (split-K x4)
  {
    const float* pb = F(8+16*1+15) + (size_t)5*768;
    const float* gf = F(40);
    const float* bf = F(41);
    void* a3[] = {(void*)&x, (void*)&P2, (void*)&pb, (void*)&gf, (void*)&bf,
                  (void*)&xf, (void*)&hutd, (void*)&HP};
    hipLaunchCooperativeKernel((const void*)coop_head_k, dim3(512), dim3(256), a3, 0, stream);
  }
  headred_k<<<dim3(512), dim3(256), 0, stream>>>(HP, outp);
}

// Round 14
// 1226.919 us; speedup vs baseline: 2.5091x; 2.5091x over previous
//
#include <hip/hip_runtime.h>
#include <cmath>

typedef unsigned short u16;
typedef __bf16 bf16x8 __attribute__((ext_vector_type(8)));
typedef float f32x4 __attribute__((ext_vector_type(4)));
typedef float f32x16 __attribute__((ext_vector_type(16)));
typedef u16 u16x4 __attribute__((ext_vector_type(4)));
typedef u16 u16x2 __attribute__((ext_vector_type(2)));
typedef u16 u16x8 __attribute__((ext_vector_type(8)));

#define GLOAD16(g, l) __builtin_amdgcn_global_load_lds( \
    (const __attribute__((address_space(1))) unsigned int*)(g), \
    (__attribute__((address_space(3))) unsigned int*)(l), 16, 0, 0)

__device__ __forceinline__ u16 f2b(float f) {
  unsigned u = __builtin_bit_cast(unsigned, f);
  unsigned r = (u + 0x7fffu + ((u >> 16) & 1u)) >> 16;
  return (u16)r;
}

// XCD-aware bijective swizzle (m204)
__device__ __forceinline__ int xcd_swz(int lin, int nwg) {
  int q = nwg >> 3, r = nwg & 7;
  int xcd = lin & 7, idx = lin >> 3;
  return xcd * q + (xcd < r ? xcd : r) + idx;
}

// ---------------- 32x32 transpose tile (fallback path only)
__device__ __forceinline__ void trans_tile(const float* __restrict__ W, u16* __restrict__ Wo,
                                           int K, int N, int Kp, int n0, int k0)
{
  __shared__ float t[32][33];
  int tx = threadIdx.x & 31, ty = threadIdx.x >> 5;
  #pragma unroll
  for (int i = 0; i < 4; ++i) {
    int k = k0 + ty + i * 8;
    t[ty + i * 8][tx] = (k < K) ? W[(long)k * N + n0 + tx] : 0.0f;
  }
  __syncthreads();
  #pragma unroll
  for (int i = 0; i < 2; ++i) {
    int p = threadIdx.x + 256 * i;
    int nl = p >> 4, kk = (p & 15) * 2;
    u16x2 o2; o2[0] = f2b(t[kk][nl]); o2[1] = f2b(t[kk + 1][nl]);
    *(u16x2*)(Wo + (long)(n0 + nl) * Kp + k0 + kk) = o2;
  }
}

// ---------------- single batched transpose, 64x64 tiles, formula-addressed
__global__ __launch_bounds__(256)
void transall_k(const float* wq0, const float* wk0, const float* wv0, const float* wo0,
                const float* fc0, const float* pr0,
                const float* wq1, const float* wk1, const float* wv1, const float* wo1,
                const float* fc1, const float* pr1,
                const float* hu, const float* hd, const float* cw,
                u16* qkvt, u16* wot, u16* fct, u16* prt, u16* hutd, u16* cwt)
{
  int bid = blockIdx.x;
  const float* src; u16* dst; int K, N, Kp, t, tilesX;
  if (bid < 20736) {
    int l = bid / 1728, local = bid - l * 1728;
    int s = l / 6, li = l - s * 6;
    if (local < 432) {
      int p = local / 144; t = local - p * 144;
      const float* base = (p == 0) ? (s ? wq1 : wq0) : (p == 1) ? (s ? wk1 : wk0) : (s ? wv1 : wv0);
      src = base + (size_t)li * 768 * 768;
      dst = qkvt + (size_t)l * 2304 * 768 + (size_t)p * 768 * 768;
      K = 768; N = 768; Kp = 768; tilesX = 12;
    } else if (local < 576) {
      t = local - 432;
      src = (s ? wo1 : wo0) + (size_t)li * 768 * 768;
      dst = wot + (size_t)l * 768 * 768;
      K = 768; N = 768; Kp = 768; tilesX = 12;
    } else if (local < 1152) {
      t = local - 576;
      src = (s ? fc1 : fc0) + (size_t)li * 768 * 3072;
      dst = fct + (size_t)l * 3072 * 768;
      K = 768; N = 3072; Kp = 768; tilesX = 48;
    } else {
      t = local - 1152;
      src = (s ? pr1 : pr0) + (size_t)li * 3072 * 768;
      dst = prt + (size_t)l * 768 * 3072;
      K = 3072; N = 768; Kp = 3072; tilesX = 12;
    }
  } else {
    int e = bid - 20736;
    if (e < 96)       { t = e;       src = hu; dst = hutd;             K = 768; N = 512; Kp = 768; tilesX = 8; }
    else if (e < 192) { t = e - 96;  src = hd; dst = hutd + 512 * 768; K = 768; N = 512; Kp = 768; tilesX = 8; }
    else              { t = e - 192; src = cw; dst = cwt;              K = 438; N = 768; Kp = 448; tilesX = 12; }
  }
  int n0 = (t % tilesX) * 64, k0 = (t / tilesX) * 64;

  __shared__ float tl[64][65];
  const int tid = threadIdx.x;
  const int c4 = (tid & 15) * 4, rbase = tid >> 4;
  #pragma unroll
  for (int p = 0; p < 4; ++p) {
    int r = rbase + p * 16;
    int k = k0 + r;
    float4 v = make_float4(0.0f, 0.0f, 0.0f, 0.0f);
    if (k < K) v = *(const float4*)(src + (long)k * N + n0 + c4);
    tl[r][c4] = v.x; tl[r][c4 + 1] = v.y; tl[r][c4 + 2] = v.z; tl[r][c4 + 3] = v.w;
  }
  __syncthreads();
  const int kg = (tid & 7) * 8, nbase = tid >> 3;
  #pragma unroll
  for (int p = 0; p < 2; ++p) {
    int n = nbase + p * 32;
    u16x8 pk;
    #pragma unroll
    for (int j = 0; j < 8; ++j) pk[j] = f2b(tl[kg + j][n]);
    *(u16x8*)(dst + (long)(n0 + n) * Kp + k0 + kg) = pk;
  }
}

// single-matrix transpose (fallback !up path)
__global__ __launch_bounds__(256)
void transw_k(const float* __restrict__ W, u16* __restrict__ Wt,
              int K, int N, int Kp, long sIn, long sOut)
{
  int l = blockIdx.z;
  trans_tile(W + (long)l * sIn, Wt + (long)l * sOut, K, N, Kp, blockIdx.x * 32, blockIdx.y * 32);
}

// ---------------- merged prologue: biascat | condcvt x4 | embed f4
__global__ __launch_bounds__(256)
void prep_k(const float* bq0, const float* bk0, const float* bv0,
            const float* bq1, const float* bk1, const float* bv1, float* qkvb,
            const float* cond, u16* cbf,
            const int* iu, const int* idn, const float* teu, const float* ted,
            const float* pe, float* x)
{
  int idx = blockIdx.x * 256 + threadIdx.x;
  if (idx < 27648) {
    int c = idx % 2304, l = idx / 2304;
    int st = l / 6, li = l % 6;
    const float* src = (c < 768) ? (st ? bq1 : bq0) : (c < 1536) ? (st ? bk1 : bk0) : (st ? bv1 : bv0);
    qkvb[idx] = src[li * 768 + (c % 768)];
  } else if (idx < 27648 + 57344) {
    int i2 = idx - 27648;
    int r = i2 / 112, kk = (i2 - r * 112) * 4;
    u16x4 pk;
    #pragma unroll
    for (int i = 0; i < 4; ++i) { int k = kk + i; pk[i] = f2b(k < 438 ? cond[r * 438 + k] : 0.0f); }
    *(u16x4*)(cbf + r * 448 + kk) = pk;
  } else if (idx < 27648 + 57344 + 196608) {
    int i3 = idx - 27648 - 57344;
    int c4 = i3 % 192; int rest = i3 / 192;
    int tt = rest % 512; int b = rest / 512;
    int i = tt & 255; int s = tt >> 8;
    int tok = s ? idn[b * 256 + i] : iu[b * 256 + i];
    const float4* src = (const float4*)(s ? (ted + (long)tok * 768) : (teu + (long)tok * 768));
    int prow = 256 + s * 256 + i;
    float4 pv = ((const float4*)(pe + (long)prow * 768))[c4];
    float4 sv = src[c4];
    float4 ov; ov.x = sv.x + pv.x; ov.y = sv.y + pv.y; ov.z = sv.z + pv.z; ov.w = sv.w + pv.w;
    ((float4*)(x + ((long)b * 768 + prow) * 768))[c4] = ov;
  }
}

// ---------------- fused split-K reduce + residual + bias + LayerNorm (float4-vectorized)
template<int S, bool WX>
__global__ __launch_bounds__(256)
void lnred_k(const float* __restrict__ xin, const float* __restrict__ P,
             const float* __restrict__ bias, const float* __restrict__ gg,
             const float* __restrict__ bb, float* __restrict__ xout,
             u16* __restrict__ h)
{
  int row = blockIdx.x * 4 + (threadIdx.x >> 6);
  int lane = threadIdx.x & 63;
  long base = (long)row * 768;
  const float4* xr4 = (const float4*)(xin + base);
  float4 v[3]; float s = 0.0f;
  #pragma unroll
  for (int j = 0; j < 3; ++j) {
    int f = lane + 64 * j;
    float4 val = xr4[f];
    if (S > 0) {
      float4 bv = ((const float4*)bias)[f];
      val.x += bv.x; val.y += bv.y; val.z += bv.z; val.w += bv.w;
      #pragma unroll
      for (int si = 0; si < S; ++si) {
        float4 pv = ((const float4*)(P + (long)si * 1179648 + base))[f];
        val.x += pv.x; val.y += pv.y; val.z += pv.z; val.w += pv.w;
      }
    }
    if (WX) ((float4*)(xout + base))[f] = val;
    v[j] = val; s += val.x + val.y + val.z + val.w;
  }
  #pragma unroll
  for (int d = 1; d < 64; d <<= 1) s += __shfl_xor(s, d);
  float mean = s * (1.0f / 768.0f);
  float s2 = 0.0f;
  #pragma unroll
  for (int j = 0; j < 3; ++j) {
    float dx = v[j].x - mean, dy = v[j].y - mean, dz = v[j].z - mean, dw = v[j].w - mean;
    s2 += dx * dx + dy * dy + dz * dz + dw * dw;
  }
  #pragma unroll
  for (int d = 1; d < 64; d <<= 1) s2 += __shfl_xor(s2, d);
  float rstd = rsqrtf(s2 * (1.0f / 768.0f) + 1e-5f);
  u16* orow = h + base;
  #pragma unroll
  for (int j = 0; j < 3; ++j) {
    int f = lane + 64 * j;
    float4 gv = ((const float4*)gg)[f];
    float4 bv2 = ((const float4*)bb)[f];
    u16x4 pk;
    pk[0] = f2b((v[j].x - mean) * rstd * gv.x + bv2.x);
    pk[1] = f2b((v[j].y - mean) * rstd * gv.y + bv2.y);
    pk[2] = f2b((v[j].z - mean) * rstd * gv.z + bv2.z);
    pk[3] = f2b((v[j].w - mean) * rstd * gv.w + bv2.w);
    *(u16x4*)(orow + 4 * f) = pk;
  }
}

// ---------------- heads reduce: HP [4][512][1024] -> out [2][512][512]
__global__ __launch_bounds__(256)
void headred_k(const float* __restrict__ HP, float* __restrict__ out)
{
  int i4 = blockIdx.x * 256 + threadIdx.x;
  int st = i4 >> 16, loc = i4 & 65535;
  int r = loc >> 7, c4 = loc & 127;
  const float4* basep = (const float4*)HP + (long)r * 256 + st * 128 + c4;
  float4 a = basep[0], b = basep[131072], c = basep[2 * 131072], d = basep[3 * 131072];
  float4 rr; rr.x = a.x + b.x + c.x + d.x; rr.y = a.y + b.y + c.y + d.y;
  rr.z = a.z + b.z + c.z + d.z; rr.w = a.w + b.w + c.w + d.w;
  ((float4*)out)[i4] = rr;
}

// ---------------- GEMM: C[M,N] = A[M,K](bf16) @ Bt[N,K](bf16)^T
// 32x32x16 MFMA; ring-2 LDS, XCD swizzle
#define EPI_PLAIN 0
#define EPI_PE    1
#define EPI_QKV   2
#define EPI_GELU  4
#define EPI_PART  5
#define EPI_HEAD  6

template<int BM, int BN, int WM, int WN, int EPI, bool BIAS>
__global__ __launch_bounds__(256)
void gemm_k(const u16* __restrict__ A, const u16* __restrict__ Bt, const float* __restrict__ bias,
            float* outf, u16* outb, u16* qb, u16* kb, u16* vT, const float* aux,
            int M, int N, int Ks, int lda, int ldb, int ldc,
            int astr, int aoff, int cstr, int coff, int pstr)
{
  constexpr int NWC = BN / WN;
  constexpr int NT  = (BM / WM) * NWC * 64;
  constexpr int LCH = (BM + BN) * 8;
  constexpr int LPT = LCH / NT;
  constexpr int MR = WM / 32, NR = WN / 32;
  __shared__ alignas(16) u16 Sl[2][(BM + BN) * 64];

  const int tid = threadIdx.x;
  const int gx = gridDim.x, gy = gridDim.y;
  const int nwg = gx * gy * gridDim.z;
  const int lin = (blockIdx.z * gy + blockIdx.y) * gx + blockIdx.x;
  const int wg = xcd_swz(lin, nwg);
  const int bx = wg % gx, t1g = wg / gx;
  const int by = t1g % gy, bz = t1g / gy;
  const int m0 = bx * BM, n0 = by * BN;
  const int koff = bz * Ks;
  const int lane = tid & 63, w = tid >> 6;
  const int l31 = lane & 31, hl = lane >> 5;
  const int wr = w / NWC, wc = w % NWC;
  int aoffE = aoff;
  if constexpr (EPI == EPI_HEAD) aoffE += (by >= (int)(gy >> 1)) ? 256 : 0;

  const u16* gp[LPT]; int lbase[LPT];
  #pragma unroll
  for (int j = 0; j < LPT; ++j) {
    int c = tid + NT * j;
    int slot = c & 7;
    if (c < BM * 8) {
      int row = c >> 3;
      int se = (slot ^ (row & 7)) * 8;
      int am = m0 + row;
      gp[j] = A + (long)((am >> 8) * astr + aoffE + (am & 255)) * lda + koff + se;
    } else {
      int rb = c - BM * 8;
      int row = rb >> 3;
      int se = (slot ^ (row & 7)) * 8;
      gp[j] = Bt + (long)(n0 + row) * ldb + koff + se;
    }
    lbase[j] = w * 512 + NT * 8 * j;
  }

  int offA[4][MR], offB[4][NR];
  #pragma unroll
  for (int kst = 0; kst < 4; ++kst) {
    int s = 2 * kst + hl;
    #pragma unroll
    for (int mi = 0; mi < MR; ++mi) {
      int r = wr * WM + mi * 32 + l31;
      offA[kst][mi] = r * 128 + ((s ^ (r & 7)) << 4);
    }
    #pragma unroll
    for (int ni = 0; ni < NR; ++ni) {
      int r = wc * WN + ni * 32 + l31;
      offB[kst][ni] = BM * 128 + r * 128 + ((s ^ (r & 7)) << 4);
    }
  }

  f32x16 acc[MR][NR];
  #pragma unroll
  for (int mi = 0; mi < MR; ++mi)
  #pragma unroll
  for (int ni = 0; ni < NR; ++ni) acc[mi][ni] = f32x16{};

  auto STAGE = [&](int kt, int buf) {
    #pragma unroll
    for (int j = 0; j < LPT; ++j) GLOAD16(gp[j] + kt, &Sl[buf][lbase[j]]);
  };
  auto COMPUTE = [&](int buf) {
    const char* Sb = (const char*)&Sl[buf][0];
    #pragma unroll
    for (int kst = 0; kst < 4; ++kst) {
      bf16x8 a[MR], b[NR];
      #pragma unroll
      for (int mi = 0; mi < MR; ++mi) a[mi] = *(const bf16x8*)(Sb + offA[kst][mi]);
      #pragma unroll
      for (int ni = 0; ni < NR; ++ni) b[ni] = *(const bf16x8*)(Sb + offB[kst][ni]);
      #pragma unroll
      for (int mi = 0; mi < MR; ++mi)
      #pragma unroll
      for (int ni = 0; ni < NR; ++ni)
        acc[mi][ni] = __builtin_amdgcn_mfma_f32_32x32x16_bf16(a[mi], b[ni], acc[mi][ni], 0, 0, 0);
    }
  };

  const int nIter = Ks >> 6;
  STAGE(0, 0);
  if (nIter > 1) STAGE(64, 1);
  for (int t = 0; t < nIter; ++t) {
    if (t + 1 < nIter) {
      if constexpr (LPT == 8)      asm volatile("s_waitcnt vmcnt(8)" ::: "memory");
      else if constexpr (LPT == 6) asm volatile("s_waitcnt vmcnt(6)" ::: "memory");
      else                         asm volatile("s_waitcnt vmcnt(4)" ::: "memory");
    } else {
      asm volatile("s_waitcnt vmcnt(0)" ::: "memory");
    }
    __builtin_amdgcn_s_barrier();
    COMPUTE(t & 1);
    if (t + 2 < nIter) {
      __builtin_amdgcn_s_barrier();
      STAGE((t + 2) << 6, t & 1);
    }
  }

  // C/D layout (32x32): col = lane&31, row = (reg&3) + 8*(reg>>2) + 4*(lane>>5)
  #pragma unroll
  for (int mi = 0; mi < MR; ++mi)
  #pragma unroll
  for (int ni = 0; ni < NR; ++ni) {
    f32x16 a = acc[mi][ni];
    int col = n0 + wc * WN + ni * 32 + l31;
    float bv = BIAS ? bias[col] : 0.0f;
    int mlb = m0 + wr * WM + mi * 32 + 4 * hl;
    if constexpr (EPI == EPI_QKV) {
      if (col >= 1536) {
        int c2 = col - 1536, hh = c2 >> 6, dd = c2 & 63;
        #pragma unroll
        for (int q = 0; q < 4; ++q) {
          int t0r = mlb + 8 * q;
          int bb2 = t0r >= 768 ? 1 : 0;
          int t0 = t0r - bb2 * 768;
          u16x4 pk;
          #pragma unroll
          for (int r = 0; r < 4; ++r) pk[r] = f2b(a[4 * q + r] + bv);
          *(u16x4*)(vT + (long)((bb2 * 12 + hh) * 64 + dd) * 768 + t0) = pk;
        }
      } else {
        u16* dst = (col < 768) ? (qb + col) : (kb + (col - 768));
        #pragma unroll
        for (int q = 0; q < 4; ++q)
        #pragma unroll
        for (int r = 0; r < 4; ++r) {
          int row = mlb + 8 * q + r;
          dst[(long)row * 768] = f2b(a[4 * q + r] + bv);
        }
      }
    } else {
      #pragma unroll
      for (int q = 0; q < 4; ++q)
      #pragma unroll
      for (int r = 0; r < 4; ++r) {
        int rg = mlb + 8 * q + r;
        long crow = (long)(rg >> 8) * cstr + coff + (rg & 255);
        float v = a[4 * q + r] + bv;
        if (EPI == EPI_PLAIN)      outf[crow * ldc + col] = v;
        else if (EPI == EPI_PE)    outf[crow * ldc + col] = v + aux[(long)(rg & 255) * 768 + col];
        else if (EPI == EPI_PART || EPI == EPI_HEAD)
                                   outf[(long)bz * pstr + (long)rg * ldc + col] = v;
        else if (EPI == EPI_GELU)  outb[crow * ldc + col] = f2b(0.5f * v * (1.0f + erff(v * 0.70710678f)));
      }
    }
  }
}

// ---------------- flash attention: 32 q-rows / 2 waves per WG, masked-tile skipping
#define MFMA_BF16 __builtin_amdgcn_mfma_f32_16x16x32_bf16
__global__ __launch_bounds__(128)
void attn_k(const u16* __restrict__ qb, const u16* __restrict__ kb,
            const u16* __restrict__ vT, u16* __restrict__ y)
{
  __shared__ alignas(16) u16 Kl[3 * 4096];
  __shared__ alignas(16) u16 Vl[3 * 4096];
  __shared__ alignas(16) u16 Pl[2][16 * 72];
  const int gx = gridDim.x, gy = gridDim.y;
  const int nwg = gx * gy;
  const int lin = blockIdx.y * gx + blockIdx.x;
  const int wg = xcd_swz(lin, nwg);
  const int qt = wg % gx, bh = wg / gx;
  const int b = bh / 12, h = bh - b * 12;
  const int tid = threadIdx.x, w = tid >> 6, lane = tid & 63, l15 = lane & 15, g = lane >> 4;
  const int qrow = qt * 32 + w * 16 + l15;
  const int qm = qrow & 255;
  const int q0 = (qt * 32) & 255;
  const unsigned nw4 = (q0 >> 6) + 1;
  const int niter = 3 * nw4;
  const u16* qp = qb + (long)(b * 768 + qrow) * 768 + h * 64;
  bf16x8 qf0 = *(const bf16x8*)(qp + 8 * g);
  bf16x8 qf1 = *(const bf16x8*)(qp + 32 + 8 * g);
  f32x4 O0{}, O1{}, O2{}, O3{};
  float m_run = -1e30f, l_run = 0.0f;

  const u16* kp[4]; const u16* vp[4]; int ldsb[4];
  #pragma unroll
  for (int j = 0; j < 4; ++j) {
    int i = tid + 128 * j;
    int r = i >> 3, sl = ((i & 7) ^ (r & 7)) * 8;
    kp[j] = kb + (long)(b * 768 + r) * 768 + h * 64 + sl;
    vp[j] = vT + (long)(bh * 64 + r) * 768 + sl;
    ldsb[j] = (w + 2 * j) * 512;
  }

  auto STAGE = [&](int kt, int q) {
    u16* kd = Kl + q * 4096; u16* vd = Vl + q * 4096;
    #pragma unroll
    for (int j = 0; j < 4; ++j) GLOAD16(kp[j] + (long)kt * 64 * 768, kd + ldsb[j]);
    #pragma unroll
    for (int j = 0; j < 4; ++j) GLOAD16(vp[j] + kt * 64, vd + ldsb[j]);
  };
  auto MAP = [&](int it) {
    unsigned sb = (unsigned)it / nw4;
    return (int)(sb * 4 + ((unsigned)it - sb * nw4));
  };

  STAGE(MAP(0), 0);
  STAGE(MAP(1), 1);
  int cur = 0;
  for (int it = 0; it < niter; ++it) {
    if (it < niter - 1) asm volatile("s_waitcnt vmcnt(8)" ::: "memory");
    else                asm volatile("s_waitcnt vmcnt(0)" ::: "memory");
    __builtin_amdgcn_s_barrier();
    if (it + 2 < niter) STAGE(MAP(it + 2), cur == 0 ? 2 : cur - 1);
    const int kt = MAP(it);
    const char* Kb = (const char*)Kl + cur * 8192;
    const char* Vb = (const char*)Vl + cur * 8192;

    f32x4 s0{}, s1{}, s2{}, s3{};
    #pragma unroll
    for (int ks = 0; ks < 2; ++ks) {
      bf16x8 qf = ks ? qf1 : qf0;
      int sb = ((4 * ks + g) ^ (l15 & 7)) << 4;
      bf16x8 k0 = *(const bf16x8*)(Kb + (0  + l15) * 128 + sb);
      bf16x8 k1 = *(const bf16x8*)(Kb + (16 + l15) * 128 + sb);
      bf16x8 k2 = *(const bf16x8*)(Kb + (32 + l15) * 128 + sb);
      bf16x8 k3 = *(const bf16x8*)(Kb + (48 + l15) * 128 + sb);
      s0 = MFMA_BF16(k0, qf, s0, 0, 0, 0);
      s1 = MFMA_BF16(k1, qf, s1, 0, 0, 0);
      s2 = MFMA_BF16(k2, qf, s2, 0, 0, 0);
      s3 = MFMA_BF16(k3, qf, s3, 0, 0, 0);
    }
    float sv[16]; float tm = -1e30f;
    #pragma unroll
    for (int mt = 0; mt < 4; ++mt) {
      f32x4 sm4 = (mt == 0) ? s0 : (mt == 1) ? s1 : (mt == 2) ? s2 : s3;
      #pragma unroll
      for (int r = 0; r < 4; ++r) {
        int kg = kt * 64 + mt * 16 + 4 * g + r;
        float val = ((kg & 255) <= qm) ? sm4[r] * 0.125f : -1e30f;
        sv[mt * 4 + r] = val; tm = fmaxf(tm, val);
      }
    }
    tm = fmaxf(tm, __shfl_xor(tm, 16));
    tm = fmaxf(tm, __shfl_xor(tm, 32));
    float mn = fmaxf(m_run, tm);
    float alpha = __expf(m_run - mn);
    float ps = 0.0f; u16 pb16[16];
    #pragma unroll
    for (int j = 0; j < 16; ++j) {
      float p = (sv[j] <= -1e29f) ? 0.0f : __expf(sv[j] - mn);
      ps += p; pb16[j] = f2b(p);
    }
    ps += __shfl_xor(ps, 16); ps += __shfl_xor(ps, 32);
    l_run = l_run * alpha + ps; m_run = mn;
    float a0 = __shfl(alpha, 4 * g + 0);
    float a1 = __shfl(alpha, 4 * g + 1);
    float a2 = __shfl(alpha, 4 * g + 2);
    float a3 = __shfl(alpha, 4 * g + 3);
    #pragma unroll
    for (int mt = 0; mt < 4; ++mt) {
      u16x4 pk; pk[0] = pb16[4*mt]; pk[1] = pb16[4*mt+1]; pk[2] = pb16[4*mt+2]; pk[3] = pb16[4*mt+3];
      *(u16x4*)((char*)&Pl[w][0] + l15 * 144 + mt * 32 + 8 * g) = pk;
    }
    O0[0] *= a0; O0[1] *= a1; O0[2] *= a2; O0[3] *= a3;
    O1[0] *= a0; O1[1] *= a1; O1[2] *= a2; O1[3] *= a3;
    O2[0] *= a0; O2[1] *= a1; O2[2] *= a2; O2[3] *= a3;
    O3[0] *= a0; O3[1] *= a1; O3[2] *= a2; O3[3] *= a3;
    asm volatile("s_waitcnt lgkmcnt(0)" ::: "memory");
    __builtin_amdgcn_sched_barrier(0);
    #pragma unroll
    for (int ks = 0; ks < 2; ++ks) {
      bf16x8 pf = *(const bf16x8*)((const char*)&Pl[w][0] + l15 * 144 + 64 * ks + 16 * g);
      int sb = ((4 * ks + g) ^ (l15 & 7)) << 4;
      bf16x8 v0 = *(const bf16x8*)(Vb + (0  + l15) * 128 + sb);
      bf16x8 v1 = *(const bf16x8*)(Vb + (16 + l15) * 128 + sb);
      bf16x8 v2 = *(const bf16x8*)(Vb + (32 + l15) * 128 + sb);
      bf16x8 v3 = *(const bf16x8*)(Vb + (48 + l15) * 128 + sb);
      O0 = MFMA_BF16(pf, v0, O0, 0, 0, 0);
      O1 = MFMA_BF16(pf, v1, O1, 0, 0, 0);
      O2 = MFMA_BF16(pf, v2, O2, 0, 0, 0);
      O3 = MFMA_BF16(pf, v3, O3, 0, 0, 0);
    }
    cur = (cur == 2) ? 0 : cur + 1;
  }
  float n0i = 1.0f / __shfl(l_run, 4 * g + 0);
  float n1i = 1.0f / __shfl(l_run, 4 * g + 1);
  float n2i = 1.0f / __shfl(l_run, 4 * g + 2);
  float n3i = 1.0f / __shfl(l_run, 4 * g + 3);
  long yr = (long)(b * 768 + qt * 32 + w * 16 + 4 * g);
  #pragma unroll
  for (int ni = 0; ni < 4; ++ni) {
    f32x4 Ov = (ni == 0) ? O0 : (ni == 1) ? O1 : (ni == 2) ? O2 : O3;
    int c = h * 64 + ni * 16 + l15;
    y[(yr + 0) * 768 + c] = f2b(Ov[0] * n0i);
    y[(yr + 1) * 768 + c] = f2b(Ov[1] * n1i);
    y[(yr + 2) * 768 + c] = f2b(Ov[2] * n2i);
    y[(yr + 3) * 768 + c] = f2b(Ov[3] * n3i);
  }
}

// ================= host =================
extern "C" void kernel_launch(void* const* d_in, const int* in_sizes, int n_in,
                              void* d_out, int out_size, void* d_ws, size_t ws_size,
                              hipStream_t stream)
{
  (void)in_sizes; (void)n_in; (void)out_size;
  auto F = [&](int i){ return (const float*)d_in[i]; };
  const int* idx_up = (const int*)d_in[0];
  const int* idx_dn = (const int*)d_in[1];
  const float* cond = F(2);
  const float* teu = F(3);
  const float* ted = F(4);
  const float* pe  = F(5);
  const float* cw  = F(6);
  const float* cb  = F(7);
  float* outp = (float*)d_out;
  char* ws = (char*)d_ws;

  size_t o = 0;
  auto take = [&](size_t bytes){ void* p = ws + o; o += bytes; return p; };
  float* x    = (float*)take(4718592);   // [1536][768] f32 residual stream
  u16*   h    = (u16*)take(2359296);     // LN out bf16
  u16*   qbuf = (u16*)take(2359296);
  u16*   kbuf = (u16*)take(2359296);
  u16*   vT   = (u16*)take(2359296);     // [24][64][768]
  u16*   y    = (u16*)take(2359296);
  u16*   fca  = (u16*)take(9437184);     // [1536][3072]
  u16*   xf   = (u16*)take(2359296);
  u16*   cbf  = (u16*)take(458752);      // cond bf16 [512][448]
  float* qkvb = (float*)take(110592);    // [12][2304]
  u16*   hutd = (u16*)take(1572864);     // [1024][768]
  u16*   cwt  = (u16*)take(688128);      // [768][448]
  float* P1   = (float*)take(9437184);   // proj partials  [2][1536][768]
  float* P2   = (float*)take(9437184);   // proj2 partials [2][1536][768]
  float* HP   = (float*)take(8388608);   // head partials  [4][512][1024]
  const size_t WL = 14155776;            // per-layer transposed weights (bytes)
  bool up = (ws_size >= o + 12 * WL);
  size_t nsl = up ? 12 : 1;
  u16* qkvt = (u16*)(ws + o);
  u16* wot  = qkvt + nsl * 2304 * 768;
  u16* fct  = wot  + nsl * 768 * 768;
  u16* prt  = fct  + nsl * 3072 * 768;

  auto trans = [&](const float* src, u16* dst, int K, int N, int Kp, long sIn, long sOut, int nz){
    transw_k<<<dim3(N / 32, Kp / 32, nz), dim3(256), 0, stream>>>(src, dst, K, N, Kp, sIn, sOut);
  };

  if (up) {
    transall_k<<<dim3(21012), dim3(256), 0, stream>>>(
        F(10), F(12), F(14), F(16), F(20), F(22),
        F(26), F(28), F(30), F(32), F(36), F(38),
        F(42), F(43), cw,
        qkvt, wot, fct, prt, hutd, cwt);
  } else {
    trans(F(42), hutd, 768, 512, 768, 0, 0, 1);
    trans(F(43), hutd + 512 * 768, 768, 512, 768, 0, 0, 1);
    trans(cw,    cwt, 438, 768, 448, 0, 0, 1);
  }
  // merged prologue (biascat | condcvt | embed)
  prep_k<<<dim3(1100), dim3(256), 0, stream>>>(
      F(11), F(13), F(15), F(27), F(29), F(31), qkvb,
      cond, cbf, idx_up, idx_dn, teu, ted, pe, x);
  // cond @ cond_w + cond_b + pos_emb -> x rows b*768 + (0..255)
  gemm_k<64, 64, 32, 32, EPI_PE, true><<<dim3(8, 12, 1), dim3(256), 0, stream>>>(cbf, cwt, cb,
      x, nullptr, nullptr, nullptr, nullptr, pe,
      512, 768, 448, 448, 448, 768, 256, 0, 768, 0, 0);

  for (int l = 0; l < 12; ++l) {
    int s = l / 6, li = l % 6;
    u16* qkvt_l = qkvt + (up ? (size_t)l : 0) * 2304 * 768;
    u16* wot_l  = wot  + (up ? (size_t)l : 0) * 768 * 768;
    u16* fct_l  = fct  + (up ? (size_t)l : 0) * 3072 * 768;
    u16* prt_l  = prt  + (up ? (size_t)l : 0) * 768 * 3072;
    if (!up) {
      for (int p = 0; p < 3; ++p)
        trans(F(8 + 16*s + 2 + 2*p) + (size_t)li*768*768, qkvt_l + (size_t)p*768*768, 768, 768, 768, 0, 0, 1);
      trans(F(8 + 16*s + 8)  + (size_t)li*768*768,  wot_l, 768, 768, 768, 0, 0, 1);
      trans(F(8 + 16*s + 12) + (size_t)li*768*3072, fct_l, 768, 3072, 768, 0, 0, 1);
      trans(F(8 + 16*s + 14) + (size_t)li*3072*768, prt_l, 3072, 768, 3072, 0, 0, 1);
    }
    // LN1 fused with previous layer's proj2 split-K(2) reduce + residual
    if (l == 0) {
      lnred_k<0, false><<<dim3(384), dim3(256), 0, stream>>>(x, nullptr, nullptr,
          F(8+16*s+0) + (size_t)li*768, F(8+16*s+1) + (size_t)li*768, nullptr, h);
    } else {
      int ps = (l - 1) / 6, pli = (l - 1) % 6;
      lnred_k<2, true><<<dim3(384), dim3(256), 0, stream>>>(x, P2,
          F(8+16*ps+15) + (size_t)pli*768,
          F(8+16*s+0) + (size_t)li*768, F(8+16*s+1) + (size_t)li*768, x, h);
    }
    gemm_k<128, 64, 32, 64, EPI_QKV, true><<<dim3(12, 36, 1), dim3(256), 0, stream>>>(h, qkvt_l, qkvb + (size_t)l*2304,
        nullptr, nullptr, qbuf, kbuf, vT, nullptr,
        1536, 2304, 768, 768, 768, 768, 256, 0, 256, 0, 0);
    attn_k<<<dim3(24, 24), dim3(128), 0, stream>>>(qbuf, kbuf, vT, y);
    // attn out proj: split-K x2 -> P1
    gemm_k<128, 64, 32, 64, EPI_PART, false><<<dim3(12, 12, 2), dim3(256), 0, stream>>>(y, wot_l, nullptr,
        P1, nullptr, nullptr, nullptr, nullptr, nullptr,
        1536, 768, 384, 768, 768, 768, 256, 0, 256, 0, 1179648);
    // LN2 fused with proj reduce + residual + bo
    lnred_k<2, true><<<dim3(384), dim3(256), 0, stream>>>(x, P1,
        F(8+16*s+9) + (size_t)li*768,
        F(8+16*s+10) + (size_t)li*768, F(8+16*s+11) + (size_t)li*768, x, h);
    gemm_k<128, 64, 32, 64, EPI_GELU, true><<<dim3(12, 48, 1), dim3(256), 0, stream>>>(h, fct_l, F(8+16*s+13) + (size_t)li*3072,
        nullptr, fca, nullptr, nullptr, nullptr, nullptr,
        1536, 3072, 768, 768, 768, 3072, 256, 0, 256, 0, 0);
    // MLP out proj: split-K x2 -> P2 (reduced by next lnred / ln_f)
    gemm_k<128, 64, 32, 64, EPI_PART, false><<<dim3(12, 12, 2), dim3(256), 0, stream>>>(fca, prt_l, nullptr,
        P2, nullptr, nullptr, nullptr, nullptr, nullptr,
        1536, 768, 1536, 3072, 3072, 768, 256, 0, 256, 0, 1179648);
  }
  // ln_f fused with last proj2 reduce (x not needed afterwards)
  lnred_k<2, false><<<dim3(384), dim3(256), 0, stream>>>(x, P2,
      F(8+16*1+15) + (size_t)5*768, F(40), F(41), nullptr, xf);
  // heads: one merged GEMM (N=1024 over both heads), split-K x4, then fused reduce
  gemm_k<64, 64, 32, 32, EPI_HEAD, false><<<dim3(8, 16, 4), dim3(256), 0, stream>>>(xf, hutd, nullptr,
      HP, nullptr, nullptr, nullptr, nullptr, nullptr,
      512, 1024, 192, 768, 768, 1024, 768, 256, 256, 0, 524288);
  headred_k<<<dim3(512), dim3(256), 0, stream>>>(HP, outp);
}

// Round 15
// 1224.788 us; speedup vs baseline: 2.5134x; 1.0017x over previous
//
#include <hip/hip_runtime.h>
#include <cmath>

typedef unsigned short u16;
typedef __bf16 bf16x8 __attribute__((ext_vector_type(8)));
typedef float f32x4 __attribute__((ext_vector_type(4)));
typedef float f32x16 __attribute__((ext_vector_type(16)));
typedef u16 u16x4 __attribute__((ext_vector_type(4)));
typedef u16 u16x2 __attribute__((ext_vector_type(2)));
typedef u16 u16x8 __attribute__((ext_vector_type(8)));

#define GLOAD16(g, l) __builtin_amdgcn_global_load_lds( \
    (const __attribute__((address_space(1))) unsigned int*)(g), \
    (__attribute__((address_space(3))) unsigned int*)(l), 16, 0, 0)

__device__ __forceinline__ u16 f2b(float f) {
  unsigned u = __builtin_bit_cast(unsigned, f);
  unsigned r = (u + 0x7fffu + ((u >> 16) & 1u)) >> 16;
  return (u16)r;
}

// XCD-aware bijective swizzle (m204)
__device__ __forceinline__ int xcd_swz(int lin, int nwg) {
  int q = nwg >> 3, r = nwg & 7;
  int xcd = lin & 7, idx = lin >> 3;
  return xcd * q + (xcd < r ? xcd : r) + idx;
}

// ---------------- 32x32 transpose tile (fallback path only)
__device__ __forceinline__ void trans_tile(const float* __restrict__ W, u16* __restrict__ Wo,
                                           int K, int N, int Kp, int n0, int k0)
{
  __shared__ float t[32][33];
  int tx = threadIdx.x & 31, ty = threadIdx.x >> 5;
  #pragma unroll
  for (int i = 0; i < 4; ++i) {
    int k = k0 + ty + i * 8;
    t[ty + i * 8][tx] = (k < K) ? W[(long)k * N + n0 + tx] : 0.0f;
  }
  __syncthreads();
  #pragma unroll
  for (int i = 0; i < 2; ++i) {
    int p = threadIdx.x + 256 * i;
    int nl = p >> 4, kk = (p & 15) * 2;
    u16x2 o2; o2[0] = f2b(t[kk][nl]); o2[1] = f2b(t[kk + 1][nl]);
    *(u16x2*)(Wo + (long)(n0 + nl) * Kp + k0 + kk) = o2;
  }
}

// ---------------- batched transpose, 64x128 macro-tiles, reg double-buffered
// per-layer tiles: qkv 216 | wo 72 | fc 288 | pr 288 = 864; 12 layers = 10368
// extras: hu 48, hd 48, cw 42 -> total 10506 blocks
__global__ __launch_bounds__(256)
void transall_k(const float* wq0, const float* wk0, const float* wv0, const float* wo0,
                const float* fc0, const float* pr0,
                const float* wq1, const float* wk1, const float* wv1, const float* wo1,
                const float* fc1, const float* pr1,
                const float* hu, const float* hd, const float* cw,
                u16* qkvt, u16* wot, u16* fct, u16* prt, u16* hutd, u16* cwt)
{
  int bid = blockIdx.x;
  const float* src; u16* dst; int K, N, Kp, t, tilesX;
  if (bid < 10368) {
    int l = bid / 864, local = bid - l * 864;
    int s = l / 6, li = l - s * 6;
    if (local < 216) {
      int p = local / 72; t = local - p * 72;
      const float* base = (p == 0) ? (s ? wq1 : wq0) : (p == 1) ? (s ? wk1 : wk0) : (s ? wv1 : wv0);
      src = base + (size_t)li * 768 * 768;
      dst = qkvt + (size_t)l * 2304 * 768 + (size_t)p * 768 * 768;
      K = 768; N = 768; Kp = 768; tilesX = 6;
    } else if (local < 288) {
      t = local - 216;
      src = (s ? wo1 : wo0) + (size_t)li * 768 * 768;
      dst = wot + (size_t)l * 768 * 768;
      K = 768; N = 768; Kp = 768; tilesX = 6;
    } else if (local < 576) {
      t = local - 288;
      src = (s ? fc1 : fc0) + (size_t)li * 768 * 3072;
      dst = fct + (size_t)l * 3072 * 768;
      K = 768; N = 3072; Kp = 768; tilesX = 24;
    } else {
      t = local - 576;
      src = (s ? pr1 : pr0) + (size_t)li * 3072 * 768;
      dst = prt + (size_t)l * 768 * 3072;
      K = 3072; N = 768; Kp = 3072; tilesX = 6;
    }
  } else {
    int e = bid - 10368;
    if (e < 48)       { t = e;       src = hu; dst = hutd;             K = 768; N = 512; Kp = 768; tilesX = 4; }
    else if (e < 96)  { t = e - 48;  src = hd; dst = hutd + 512 * 768; K = 768; N = 512; Kp = 768; tilesX = 4; }
    else              { t = e - 96;  src = cw; dst = cwt;              K = 438; N = 768; Kp = 448; tilesX = 6; }
  }
  int n0 = (t % tilesX) * 128, k0 = (t / tilesX) * 64;

  __shared__ float tl[64][65];
  const int tid = threadIdx.x;
  const int c4 = (tid & 15) * 4, rbase = tid >> 4;   // load: 16 rows/pass, float4/thread
  const int kg = (tid & 7) * 8, nbase = tid >> 3;    // store: 32 out-rows/pass, u16x8/thread

  // pass 0: load sub-tile (n0) -> LDS
  float4 v0[4];
  #pragma unroll
  for (int p = 0; p < 4; ++p) {
    int r = rbase + p * 16, k = k0 + r;
    v0[p] = make_float4(0.0f, 0.0f, 0.0f, 0.0f);
    if (k < K) v0[p] = *(const float4*)(src + (long)k * N + n0 + c4);
  }
  #pragma unroll
  for (int p = 0; p < 4; ++p) {
    int r = rbase + p * 16;
    tl[r][c4] = v0[p].x; tl[r][c4 + 1] = v0[p].y; tl[r][c4 + 2] = v0[p].z; tl[r][c4 + 3] = v0[p].w;
  }
  __syncthreads();

  // issue pass-1 loads (n0+64) into registers; latency hides under pass-0 pack/store
  float4 v1[4];
  #pragma unroll
  for (int p = 0; p < 4; ++p) {
    int r = rbase + p * 16, k = k0 + r;
    v1[p] = make_float4(0.0f, 0.0f, 0.0f, 0.0f);
    if (k < K) v1[p] = *(const float4*)(src + (long)k * N + n0 + 64 + c4);
  }

  // pass 0: gather + pack + store
  #pragma unroll
  for (int p = 0; p < 2; ++p) {
    int n = nbase + p * 32;
    u16x8 pk;
    #pragma unroll
    for (int j = 0; j < 8; ++j) pk[j] = f2b(tl[kg + j][n]);
    *(u16x8*)(dst + (long)(n0 + n) * Kp + k0 + kg) = pk;
  }
  __syncthreads();

  // pass 1: regs -> LDS
  #pragma unroll
  for (int p = 0; p < 4; ++p) {
    int r = rbase + p * 16;
    tl[r][c4] = v1[p].x; tl[r][c4 + 1] = v1[p].y; tl[r][c4 + 2] = v1[p].z; tl[r][c4 + 3] = v1[p].w;
  }
  __syncthreads();

  // pass 1: gather + pack + store
  #pragma unroll
  for (int p = 0; p < 2; ++p) {
    int n = nbase + p * 32;
    u16x8 pk;
    #pragma unroll
    for (int j = 0; j < 8; ++j) pk[j] = f2b(tl[kg + j][n]);
    *(u16x8*)(dst + (long)(n0 + 64 + n) * Kp + k0 + kg) = pk;
  }
}

// single-matrix transpose (fallback !up path)
__global__ __launch_bounds__(256)
void transw_k(const float* __restrict__ W, u16* __restrict__ Wt,
              int K, int N, int Kp, long sIn, long sOut)
{
  int l = blockIdx.z;
  trans_tile(W + (long)l * sIn, Wt + (long)l * sOut, K, N, Kp, blockIdx.x * 32, blockIdx.y * 32);
}

// ---------------- merged prologue: biascat | condcvt x4 | embed f4
__global__ __launch_bounds__(256)
void prep_k(const float* bq0, const float* bk0, const float* bv0,
            const float* bq1, const float* bk1, const float* bv1, float* qkvb,
            const float* cond, u16* cbf,
            const int* iu, const int* idn, const float* teu, const float* ted,
            const float* pe, float* x)
{
  int idx = blockIdx.x * 256 + threadIdx.x;
  if (idx < 27648) {
    int c = idx % 2304, l = idx / 2304;
    int st = l / 6, li = l % 6;
    const float* src = (c < 768) ? (st ? bq1 : bq0) : (c < 1536) ? (st ? bk1 : bk0) : (st ? bv1 : bv0);
    qkvb[idx] = src[li * 768 + (c % 768)];
  } else if (idx < 27648 + 57344) {
    int i2 = idx - 27648;
    int r = i2 / 112, kk = (i2 - r * 112) * 4;
    u16x4 pk;
    #pragma unroll
    for (int i = 0; i < 4; ++i) { int k = kk + i; pk[i] = f2b(k < 438 ? cond[r * 438 + k] : 0.0f); }
    *(u16x4*)(cbf + r * 448 + kk) = pk;
  } else if (idx < 27648 + 57344 + 196608) {
    int i3 = idx - 27648 - 57344;
    int c4 = i3 % 192; int rest = i3 / 192;
    int tt = rest % 512; int b = rest / 512;
    int i = tt & 255; int s = tt >> 8;
    int tok = s ? idn[b * 256 + i] : iu[b * 256 + i];
    const float4* src = (const float4*)(s ? (ted + (long)tok * 768) : (teu + (long)tok * 768));
    int prow = 256 + s * 256 + i;
    float4 pv = ((const float4*)(pe + (long)prow * 768))[c4];
    float4 sv = src[c4];
    float4 ov; ov.x = sv.x + pv.x; ov.y = sv.y + pv.y; ov.z = sv.z + pv.z; ov.w = sv.w + pv.w;
    ((float4*)(x + ((long)b * 768 + prow) * 768))[c4] = ov;
  }
}

// ---------------- fused split-K reduce + residual + bias + LayerNorm (float4-vectorized)
template<int S, bool WX>
__global__ __launch_bounds__(256)
void lnred_k(const float* __restrict__ xin, const float* __restrict__ P,
             const float* __restrict__ bias, const float* __restrict__ gg,
             const float* __restrict__ bb, float* __restrict__ xout,
             u16* __restrict__ h)
{
  int row = blockIdx.x * 4 + (threadIdx.x >> 6);
  int lane = threadIdx.x & 63;
  long base = (long)row * 768;
  const float4* xr4 = (const float4*)(xin + base);
  float4 v[3]; float s = 0.0f;
  #pragma unroll
  for (int j = 0; j < 3; ++j) {
    int f = lane + 64 * j;
    float4 val = xr4[f];
    if (S > 0) {
      float4 bv = ((const float4*)bias)[f];
      val.x += bv.x; val.y += bv.y; val.z += bv.z; val.w += bv.w;
      #pragma unroll
      for (int si = 0; si < S; ++si) {
        float4 pv = ((const float4*)(P + (long)si * 1179648 + base))[f];
        val.x += pv.x; val.y += pv.y; val.z += pv.z; val.w += pv.w;
      }
    }
    if (WX) ((float4*)(xout + base))[f] = val;
    v[j] = val; s += val.x + val.y + val.z + val.w;
  }
  #pragma unroll
  for (int d = 1; d < 64; d <<= 1) s += __shfl_xor(s, d);
  float mean = s * (1.0f / 768.0f);
  float s2 = 0.0f;
  #pragma unroll
  for (int j = 0; j < 3; ++j) {
    float dx = v[j].x - mean, dy = v[j].y - mean, dz = v[j].z - mean, dw = v[j].w - mean;
    s2 += dx * dx + dy * dy + dz * dz + dw * dw;
  }
  #pragma unroll
  for (int d = 1; d < 64; d <<= 1) s2 += __shfl_xor(s2, d);
  float rstd = rsqrtf(s2 * (1.0f / 768.0f) + 1e-5f);
  u16* orow = h + base;
  #pragma unroll
  for (int j = 0; j < 3; ++j) {
    int f = lane + 64 * j;
    float4 gv = ((const float4*)gg)[f];
    float4 bv2 = ((const float4*)bb)[f];
    u16x4 pk;
    pk[0] = f2b((v[j].x - mean) * rstd * gv.x + bv2.x);
    pk[1] = f2b((v[j].y - mean) * rstd * gv.y + bv2.y);
    pk[2] = f2b((v[j].z - mean) * rstd * gv.z + bv2.z);
    pk[3] = f2b((v[j].w - mean) * rstd * gv.w + bv2.w);
    *(u16x4*)(orow + 4 * f) = pk;
  }
}

// ---------------- heads reduce: HP [4][512][1024] -> out [2][512][512]
__global__ __launch_bounds__(256)
void headred_k(const float* __restrict__ HP, float* __restrict__ out)
{
  int i4 = blockIdx.x * 256 + threadIdx.x;
  int st = i4 >> 16, loc = i4 & 65535;
  int r = loc >> 7, c4 = loc & 127;
  const float4* basep = (const float4*)HP + (long)r * 256 + st * 128 + c4;
  float4 a = basep[0], b = basep[131072], c = basep[2 * 131072], d = basep[3 * 131072];
  float4 rr; rr.x = a.x + b.x + c.x + d.x; rr.y = a.y + b.y + c.y + d.y;
  rr.z = a.z + b.z + c.z + d.z; rr.w = a.w + b.w + c.w + d.w;
  ((float4*)out)[i4] = rr;
}

// ---------------- GEMM: C[M,N] = A[M,K](bf16) @ Bt[N,K](bf16)^T
// 32x32x16 MFMA; ring-2 LDS, XCD swizzle
#define EPI_PLAIN 0
#define EPI_PE    1
#define EPI_QKV   2
#define EPI_GELU  4
#define EPI_PART  5
#define EPI_HEAD  6

template<int BM, int BN, int WM, int WN, int EPI, bool BIAS>
__global__ __launch_bounds__(256)
void gemm_k(const u16* __restrict__ A, const u16* __restrict__ Bt, const float* __restrict__ bias,
            float* outf, u16* outb, u16* qb, u16* kb, u16* vT, const float* aux,
            int M, int N, int Ks, int lda, int ldb, int ldc,
            int astr, int aoff, int cstr, int coff, int pstr)
{
  constexpr int NWC = BN / WN;
  constexpr int NT  = (BM / WM) * NWC * 64;
  constexpr int LCH = (BM + BN) * 8;
  constexpr int LPT = LCH / NT;
  constexpr int MR = WM / 32, NR = WN / 32;
  __shared__ alignas(16) u16 Sl[2][(BM + BN) * 64];

  const int tid = threadIdx.x;
  const int gx = gridDim.x, gy = gridDim.y;
  const int nwg = gx * gy * gridDim.z;
  const int lin = (blockIdx.z * gy + blockIdx.y) * gx + blockIdx.x;
  const int wg = xcd_swz(lin, nwg);
  const int bx = wg % gx, t1g = wg / gx;
  const int by = t1g % gy, bz = t1g / gy;
  const int m0 = bx * BM, n0 = by * BN;
  const int koff = bz * Ks;
  const int lane = tid & 63, w = tid >> 6;
  const int l31 = lane & 31, hl = lane >> 5;
  const int wr = w / NWC, wc = w % NWC;
  int aoffE = aoff;
  if constexpr (EPI == EPI_HEAD) aoffE += (by >= (int)(gy >> 1)) ? 256 : 0;

  const u16* gp[LPT]; int lbase[LPT];
  #pragma unroll
  for (int j = 0; j < LPT; ++j) {
    int c = tid + NT * j;
    int slot = c & 7;
    if (c < BM * 8) {
      int row = c >> 3;
      int se = (slot ^ (row & 7)) * 8;
      int am = m0 + row;
      gp[j] = A + (long)((am >> 8) * astr + aoffE + (am & 255)) * lda + koff + se;
    } else {
      int rb = c - BM * 8;
      int row = rb >> 3;
      int se = (slot ^ (row & 7)) * 8;
      gp[j] = Bt + (long)(n0 + row) * ldb + koff + se;
    }
    lbase[j] = w * 512 + NT * 8 * j;
  }

  int offA[4][MR], offB[4][NR];
  #pragma unroll
  for (int kst = 0; kst < 4; ++kst) {
    int s = 2 * kst + hl;
    #pragma unroll
    for (int mi = 0; mi < MR; ++mi) {
      int r = wr * WM + mi * 32 + l31;
      offA[kst][mi] = r * 128 + ((s ^ (r & 7)) << 4);
    }
    #pragma unroll
    for (int ni = 0; ni < NR; ++ni) {
      int r = wc * WN + ni * 32 + l31;
      offB[kst][ni] = BM * 128 + r * 128 + ((s ^ (r & 7)) << 4);
    }
  }

  f32x16 acc[MR][NR];
  #pragma unroll
  for (int mi = 0; mi < MR; ++mi)
  #pragma unroll
  for (int ni = 0; ni < NR; ++ni) acc[mi][ni] = f32x16{};

  auto STAGE = [&](int kt, int buf) {
    #pragma unroll
    for (int j = 0; j < LPT; ++j) GLOAD16(gp[j] + kt, &Sl[buf][lbase[j]]);
  };
  auto COMPUTE = [&](int buf) {
    const char* Sb = (const char*)&Sl[buf][0];
    #pragma unroll
    for (int kst = 0; kst < 4; ++kst) {
      bf16x8 a[MR], b[NR];
      #pragma unroll
      for (int mi = 0; mi < MR; ++mi) a[mi] = *(const bf16x8*)(Sb + offA[kst][mi]);
      #pragma unroll
      for (int ni = 0; ni < NR; ++ni) b[ni] = *(const bf16x8*)(Sb + offB[kst][ni]);
      #pragma unroll
      for (int mi = 0; mi < MR; ++mi)
      #pragma unroll
      for (int ni = 0; ni < NR; ++ni)
        acc[mi][ni] = __builtin_amdgcn_mfma_f32_32x32x16_bf16(a[mi], b[ni], acc[mi][ni], 0, 0, 0);
    }
  };

  const int nIter = Ks >> 6;
  STAGE(0, 0);
  if (nIter > 1) STAGE(64, 1);
  for (int t = 0; t < nIter; ++t) {
    if (t + 1 < nIter) {
      if constexpr (LPT == 8)      asm volatile("s_waitcnt vmcnt(8)" ::: "memory");
      else if constexpr (LPT == 6) asm volatile("s_waitcnt vmcnt(6)" ::: "memory");
      else                         asm volatile("s_waitcnt vmcnt(4)" ::: "memory");
    } else {
      asm volatile("s_waitcnt vmcnt(0)" ::: "memory");
    }
    __builtin_amdgcn_s_barrier();
    COMPUTE(t & 1);
    if (t + 2 < nIter) {
      __builtin_amdgcn_s_barrier();
      STAGE((t + 2) << 6, t & 1);
    }
  }

  // C/D layout (32x32): col = lane&31, row = (reg&3) + 8*(reg>>2) + 4*(lane>>5)
  #pragma unroll
  for (int mi = 0; mi < MR; ++mi)
  #pragma unroll
  for (int ni = 0; ni < NR; ++ni) {
    f32x16 a = acc[mi][ni];
    int col = n0 + wc * WN + ni * 32 + l31;
    float bv = BIAS ? bias[col] : 0.0f;
    int mlb = m0 + wr * WM + mi * 32 + 4 * hl;
    if constexpr (EPI == EPI_QKV) {
      if (col >= 1536) {
        int c2 = col - 1536, hh = c2 >> 6, dd = c2 & 63;
        #pragma unroll
        for (int q = 0; q < 4; ++q) {
          int t0r = mlb + 8 * q;
          int bb2 = t0r >= 768 ? 1 : 0;
          int t0 = t0r - bb2 * 768;
          u16x4 pk;
          #pragma unroll
          for (int r = 0; r < 4; ++r) pk[r] = f2b(a[4 * q + r] + bv);
          *(u16x4*)(vT + (long)((bb2 * 12 + hh) * 64 + dd) * 768 + t0) = pk;
        }
      } else {
        u16* dst = (col < 768) ? (qb + col) : (kb + (col - 768));
        #pragma unroll
        for (int q = 0; q < 4; ++q)
        #pragma unroll
        for (int r = 0; r < 4; ++r) {
          int row = mlb + 8 * q + r;
          dst[(long)row * 768] = f2b(a[4 * q + r] + bv);
        }
      }
    } else {
      #pragma unroll
      for (int q = 0; q < 4; ++q)
      #pragma unroll
      for (int r = 0; r < 4; ++r) {
        int rg = mlb + 8 * q + r;
        long crow = (long)(rg >> 8) * cstr + coff + (rg & 255);
        float v = a[4 * q + r] + bv;
        if (EPI == EPI_PLAIN)      outf[crow * ldc + col] = v;
        else if (EPI == EPI_PE)    outf[crow * ldc + col] = v + aux[(long)(rg & 255) * 768 + col];
        else if (EPI == EPI_PART || EPI == EPI_HEAD)
                                   outf[(long)bz * pstr + (long)rg * ldc + col] = v;
        else if (EPI == EPI_GELU)  outb[crow * ldc + col] = f2b(0.5f * v * (1.0f + erff(v * 0.70710678f)));
      }
    }
  }
}

// ---------------- flash attention: 32 q-rows / 2 waves per WG, masked-tile skipping
#define MFMA_BF16 __builtin_amdgcn_mfma_f32_16x16x32_bf16
__global__ __launch_bounds__(128)
void attn_k(const u16* __restrict__ qb, const u16* __restrict__ kb,
            const u16* __restrict__ vT, u16* __restrict__ y)
{
  __shared__ alignas(16) u16 Kl[3 * 4096];
  __shared__ alignas(16) u16 Vl[3 * 4096];
  __shared__ alignas(16) u16 Pl[2][16 * 72];
  const int gx = gridDim.x, gy = gridDim.y;
  const int nwg = gx * gy;
  const int lin = blockIdx.y * gx + blockIdx.x;
  const int wg = xcd_swz(lin, nwg);
  const int qt = wg % gx, bh = wg / gx;
  const int b = bh / 12, h = bh - b * 12;
  const int tid = threadIdx.x, w = tid >> 6, lane = tid & 63, l15 = lane & 15, g = lane >> 4;
  const int qrow = qt * 32 + w * 16 + l15;
  const int qm = qrow & 255;
  const int q0 = (qt * 32) & 255;
  const unsigned nw4 = (q0 >> 6) + 1;
  const int niter = 3 * nw4;
  const u16* qp = qb + (long)(b * 768 + qrow) * 768 + h * 64;
  bf16x8 qf0 = *(const bf16x8*)(qp + 8 * g);
  bf16x8 qf1 = *(const bf16x8*)(qp + 32 + 8 * g);
  f32x4 O0{}, O1{}, O2{}, O3{};
  float m_run = -1e30f, l_run = 0.0f;

  const u16* kp[4]; const u16* vp[4]; int ldsb[4];
  #pragma unroll
  for (int j = 0; j < 4; ++j) {
    int i = tid + 128 * j;
    int r = i >> 3, sl = ((i & 7) ^ (r & 7)) * 8;
    kp[j] = kb + (long)(b * 768 + r) * 768 + h * 64 + sl;
    vp[j] = vT + (long)(bh * 64 + r) * 768 + sl;
    ldsb[j] = (w + 2 * j) * 512;
  }

  auto STAGE = [&](int kt, int q) {
    u16* kd = Kl + q * 4096; u16* vd = Vl + q * 4096;
    #pragma unroll
    for (int j = 0; j < 4; ++j) GLOAD16(kp[j] + (long)kt * 64 * 768, kd + ldsb[j]);
    #pragma unroll
    for (int j = 0; j < 4; ++j) GLOAD16(vp[j] + kt * 64, vd + ldsb[j]);
  };
  auto MAP = [&](int it) {
    unsigned sb = (unsigned)it / nw4;
    return (int)(sb * 4 + ((unsigned)it - sb * nw4));
  };

  STAGE(MAP(0), 0);
  STAGE(MAP(1), 1);
  int cur = 0;
  for (int it = 0; it < niter; ++it) {
    if (it < niter - 1) asm volatile("s_waitcnt vmcnt(8)" ::: "memory");
    else                asm volatile("s_waitcnt vmcnt(0)" ::: "memory");
    __builtin_amdgcn_s_barrier();
    if (it + 2 < niter) STAGE(MAP(it + 2), cur == 0 ? 2 : cur - 1);
    const int kt = MAP(it);
    const char* Kb = (const char*)Kl + cur * 8192;
    const char* Vb = (const char*)Vl + cur * 8192;

    f32x4 s0{}, s1{}, s2{}, s3{};
    #pragma unroll
    for (int ks = 0; ks < 2; ++ks) {
      bf16x8 qf = ks ? qf1 : qf0;
      int sb = ((4 * ks + g) ^ (l15 & 7)) << 4;
      bf16x8 k0 = *(const bf16x8*)(Kb + (0  + l15) * 128 + sb);
      bf16x8 k1 = *(const bf16x8*)(Kb + (16 + l15) * 128 + sb);
      bf16x8 k2 = *(const bf16x8*)(Kb + (32 + l15) * 128 + sb);
      bf16x8 k3 = *(const bf16x8*)(Kb + (48 + l15) * 128 + sb);
      s0 = MFMA_BF16(k0, qf, s0, 0, 0, 0);
      s1 = MFMA_BF16(k1, qf, s1, 0, 0, 0);
      s2 = MFMA_BF16(k2, qf, s2, 0, 0, 0);
      s3 = MFMA_BF16(k3, qf, s3, 0, 0, 0);
    }
    float sv[16]; float tm = -1e30f;
    #pragma unroll
    for (int mt = 0; mt < 4; ++mt) {
      f32x4 sm4 = (mt == 0) ? s0 : (mt == 1) ? s1 : (mt == 2) ? s2 : s3;
      #pragma unroll
      for (int r = 0; r < 4; ++r) {
        int kg = kt * 64 + mt * 16 + 4 * g + r;
        float val = ((kg & 255) <= qm) ? sm4[r] * 0.125f : -1e30f;
        sv[mt * 4 + r] = val; tm = fmaxf(tm, val);
      }
    }
    tm = fmaxf(tm, __shfl_xor(tm, 16));
    tm = fmaxf(tm, __shfl_xor(tm, 32));
    float mn = fmaxf(m_run, tm);
    float alpha = __expf(m_run - mn);
    float ps = 0.0f; u16 pb16[16];
    #pragma unroll
    for (int j = 0; j < 16; ++j) {
      float p = (sv[j] <= -1e29f) ? 0.0f : __expf(sv[j] - mn);
      ps += p; pb16[j] = f2b(p);
    }
    ps += __shfl_xor(ps, 16); ps += __shfl_xor(ps, 32);
    l_run = l_run * alpha + ps; m_run = mn;
    float a0 = __shfl(alpha, 4 * g + 0);
    float a1 = __shfl(alpha, 4 * g + 1);
    float a2 = __shfl(alpha, 4 * g + 2);
    float a3 = __shfl(alpha, 4 * g + 3);
    #pragma unroll
    for (int mt = 0; mt < 4; ++mt) {
      u16x4 pk; pk[0] = pb16[4*mt]; pk[1] = pb16[4*mt+1]; pk[2] = pb16[4*mt+2]; pk[3] = pb16[4*mt+3];
      *(u16x4*)((char*)&Pl[w][0] + l15 * 144 + mt * 32 + 8 * g) = pk;
    }
    O0[0] *= a0; O0[1] *= a1; O0[2] *= a2; O0[3] *= a3;
    O1[0] *= a0; O1[1] *= a1; O1[2] *= a2; O1[3] *= a3;
    O2[0] *= a0; O2[1] *= a1; O2[2] *= a2; O2[3] *= a3;
    O3[0] *= a0; O3[1] *= a1; O3[2] *= a2; O3[3] *= a3;
    asm volatile("s_waitcnt lgkmcnt(0)" ::: "memory");
    __builtin_amdgcn_sched_barrier(0);
    #pragma unroll
    for (int ks = 0; ks < 2; ++ks) {
      bf16x8 pf = *(const bf16x8*)((const char*)&Pl[w][0] + l15 * 144 + 64 * ks + 16 * g);
      int sb = ((4 * ks + g) ^ (l15 & 7)) << 4;
      bf16x8 v0 = *(const bf16x8*)(Vb + (0  + l15) * 128 + sb);
      bf16x8 v1 = *(const bf16x8*)(Vb + (16 + l15) * 128 + sb);
      bf16x8 v2 = *(const bf16x8*)(Vb + (32 + l15) * 128 + sb);
      bf16x8 v3 = *(const bf16x8*)(Vb + (48 + l15) * 128 + sb);
      O0 = MFMA_BF16(pf, v0, O0, 0, 0, 0);
      O1 = MFMA_BF16(pf, v1, O1, 0, 0, 0);
      O2 = MFMA_BF16(pf, v2, O2, 0, 0, 0);
      O3 = MFMA_BF16(pf, v3, O3, 0, 0, 0);
    }
    cur = (cur == 2) ? 0 : cur + 1;
  }
  float n0i = 1.0f / __shfl(l_run, 4 * g + 0);
  float n1i = 1.0f / __shfl(l_run, 4 * g + 1);
  float n2i = 1.0f / __shfl(l_run, 4 * g + 2);
  float n3i = 1.0f / __shfl(l_run, 4 * g + 3);
  long yr = (long)(b * 768 + qt * 32 + w * 16 + 4 * g);
  #pragma unroll
  for (int ni = 0; ni < 4; ++ni) {
    f32x4 Ov = (ni == 0) ? O0 : (ni == 1) ? O1 : (ni == 2) ? O2 : O3;
    int c = h * 64 + ni * 16 + l15;
    y[(yr + 0) * 768 + c] = f2b(Ov[0] * n0i);
    y[(yr + 1) * 768 + c] = f2b(Ov[1] * n1i);
    y[(yr + 2) * 768 + c] = f2b(Ov[2] * n2i);
    y[(yr + 3) * 768 + c] = f2b(Ov[3] * n3i);
  }
}

// ================= host =================
extern "C" void kernel_launch(void* const* d_in, const int* in_sizes, int n_in,
                              void* d_out, int out_size, void* d_ws, size_t ws_size,
                              hipStream_t stream)
{
  (void)in_sizes; (void)n_in; (void)out_size;
  auto F = [&](int i){ return (const float*)d_in[i]; };
  const int* idx_up = (const int*)d_in[0];
  const int* idx_dn = (const int*)d_in[1];
  const float* cond = F(2);
  const float* teu = F(3);
  const float* ted = F(4);
  const float* pe  = F(5);
  const float* cw  = F(6);
  const float* cb  = F(7);
  float* outp = (float*)d_out;
  char* ws = (char*)d_ws;

  size_t o = 0;
  auto take = [&](size_t bytes){ void* p = ws + o; o += bytes; return p; };
  float* x    = (float*)take(4718592);   // [1536][768] f32 residual stream
  u16*   h    = (u16*)take(2359296);     // LN out bf16
  u16*   qbuf = (u16*)take(2359296);
  u16*   kbuf = (u16*)take(2359296);
  u16*   vT   = (u16*)take(2359296);     // [24][64][768]
  u16*   y    = (u16*)take(2359296);
  u16*   fca  = (u16*)take(9437184);     // [1536][3072]
  u16*   xf   = (u16*)take(2359296);
  u16*   cbf  = (u16*)take(458752);      // cond bf16 [512][448]
  float* qkvb = (float*)take(110592);    // [12][2304]
  u16*   hutd = (u16*)take(1572864);     // [1024][768]
  u16*   cwt  = (u16*)take(688128);      // [768][448]
  float* P1   = (float*)take(9437184);   // proj partials  [2][1536][768]
  float* P2   = (float*)take(9437184);   // proj2 partials [2][1536][768]
  float* HP   = (float*)take(8388608);   // head partials  [4][512][1024]
  const size_t WL = 14155776;            // per-layer transposed weights (bytes)
  bool up = (ws_size >= o + 12 * WL);
  size_t nsl = up ? 12 : 1;
  u16* qkvt = (u16*)(ws + o);
  u16* wot  = qkvt + nsl * 2304 * 768;
  u16* fct  = wot  + nsl * 768 * 768;
  u16* prt  = fct  + nsl * 3072 * 768;

  auto trans = [&](const float* src, u16* dst, int K, int N, int Kp, long sIn, long sOut, int nz){
    transw_k<<<dim3(N / 32, Kp / 32, nz), dim3(256), 0, stream>>>(src, dst, K, N, Kp, sIn, sOut);
  };

  if (up) {
    transall_k<<<dim3(10506), dim3(256), 0, stream>>>(
        F(10), F(12), F(14), F(16), F(20), F(22),
        F(26), F(28), F(30), F(32), F(36), F(38),
        F(42), F(43), cw,
        qkvt, wot, fct, prt, hutd, cwt);
  } else {
    trans(F(42), hutd, 768, 512, 768, 0, 0, 1);
    trans(F(43), hutd + 512 * 768, 768, 512, 768, 0, 0, 1);
    trans(cw,    cwt, 438, 768, 448, 0, 0, 1);
  }
  // merged prologue (biascat | condcvt | embed)
  prep_k<<<dim3(1100), dim3(256), 0, stream>>>(
      F(11), F(13), F(15), F(27), F(29), F(31), qkvb,
      cond, cbf, idx_up, idx_dn, teu, ted, pe, x);
  // cond @ cond_w + cond_b + pos_emb -> x rows b*768 + (0..255)
  gemm_k<64, 64, 32, 32, EPI_PE, true><<<dim3(8, 12, 1), dim3(256), 0, stream>>>(cbf, cwt, cb,
      x, nullptr, nullptr, nullptr, nullptr, pe,
      512, 768, 448, 448, 448, 768, 256, 0, 768, 0, 0);

  for (int l = 0; l < 12; ++l) {
    int s = l / 6, li = l % 6;
    u16* qkvt_l = qkvt + (up ? (size_t)l : 0) * 2304 * 768;
    u16* wot_l  = wot  + (up ? (size_t)l : 0) * 768 * 768;
    u16* fct_l  = fct  + (up ? (size_t)l : 0) * 3072 * 768;
    u16* prt_l  = prt  + (up ? (size_t)l : 0) * 768 * 3072;
    if (!up) {
      for (int p = 0; p < 3; ++p)
        trans(F(8 + 16*s + 2 + 2*p) + (size_t)li*768*768, qkvt_l + (size_t)p*768*768, 768, 768, 768, 0, 0, 1);
      trans(F(8 + 16*s + 8)  + (size_t)li*768*768,  wot_l, 768, 768, 768, 0, 0, 1);
      trans(F(8 + 16*s + 12) + (size_t)li*768*3072, fct_l, 768, 3072, 768, 0, 0, 1);
      trans(F(8 + 16*s + 14) + (size_t)li*3072*768, prt_l, 3072, 768, 3072, 0, 0, 1);
    }
    // LN1 fused with previous layer's proj2 split-K(2) reduce + residual
    if (l == 0) {
      lnred_k<0, false><<<dim3(384), dim3(256), 0, stream>>>(x, nullptr, nullptr,
          F(8+16*s+0) + (size_t)li*768, F(8+16*s+1) + (size_t)li*768, nullptr, h);
    } else {
      int ps = (l - 1) / 6, pli = (l - 1) % 6;
      lnred_k<2, true><<<dim3(384), dim3(256), 0, stream>>>(x, P2,
          F(8+16*ps+15) + (size_t)pli*768,
          F(8+16*s+0) + (size_t)li*768, F(8+16*s+1) + (size_t)li*768, x, h);
    }
    gemm_k<128, 64, 32, 64, EPI_QKV, true><<<dim3(12, 36, 1), dim3(256), 0, stream>>>(h, qkvt_l, qkvb + (size_t)l*2304,
        nullptr, nullptr, qbuf, kbuf, vT, nullptr,
        1536, 2304, 768, 768, 768, 768, 256, 0, 256, 0, 0);
    attn_k<<<dim3(24, 24), dim3(128), 0, stream>>>(qbuf, kbuf, vT, y);
    // attn out proj: split-K x2 -> P1
    gemm_k<128, 64, 32, 64, EPI_PART, false><<<dim3(12, 12, 2), dim3(256), 0, stream>>>(y, wot_l, nullptr,
        P1, nullptr, nullptr, nullptr, nullptr, nullptr,
        1536, 768, 384, 768, 768, 768, 256, 0, 256, 0, 1179648);
    // LN2 fused with proj reduce + residual + bo
    lnred_k<2, true><<<dim3(384), dim3(256), 0, stream>>>(x, P1,
        F(8+16*s+9) + (size_t)li*768,
        F(8+16*s+10) + (size_t)li*768, F(8+16*s+11) + (size_t)li*768, x, h);
    gemm_k<128, 64, 32, 64, EPI_GELU, true><<<dim3(12, 48, 1), dim3(256), 0, stream>>>(h, fct_l, F(8+16*s+13) + (size_t)li*3072,
        nullptr, fca, nullptr, nullptr, nullptr, nullptr,
        1536, 3072, 768, 768, 768, 3072, 256, 0, 256, 0, 0);
    // MLP out proj: split-K x2 -> P2 (reduced by next lnred / ln_f)
    gemm_k<128, 64, 32, 64, EPI_PART, false><<<dim3(12, 12, 2), dim3(256), 0, stream>>>(fca, prt_l, nullptr,
        P2, nullptr, nullptr, nullptr, nullptr, nullptr,
        1536, 768, 1536, 3072, 3072, 768, 256, 0, 256, 0, 1179648);
  }
  // ln_f fused with last proj2 reduce (x not needed afterwards)
  lnred_k<2, false><<<dim3(384), dim3(256), 0, stream>>>(x, P2,
      F(8+16*1+15) + (size_t)5*768, F(40), F(41), nullptr, xf);
  // heads: one merged GEMM (N=1024 over both heads), split-K x4, then fused reduce
  gemm_k<64, 64, 32, 32, EPI_HEAD, false><<<dim3(8, 16, 4), dim3(256), 0, stream>>>(xf, hutd, nullptr,
      HP, nullptr, nullptr, nullptr, nullptr, nullptr,
      512, 1024, 192, 768, 768, 1024, 768, 256, 256, 0, 524288);
  headred_k<<<dim3(512), dim3(256), 0, stream>>>(HP, outp);
}